// Round 14
// baseline (384.128 us; speedup 1.0000x reference)
//
#include <hip/hip_runtime.h>
#include <stdint.h>

#define B_ 2
#define S_ 2048
#define H_ 16
#define HKV_ 8
#define D_ 128
#define EPS_ 1e-6f
#define SCALE_ 0.08838834764831845f
#define KVSTRIDE_ 262144   // per (b,kv): 2048*128 elems

typedef __attribute__((ext_vector_type(8))) __bf16 bf16x8;
typedef __attribute__((ext_vector_type(4))) float f32x4;
typedef __attribute__((ext_vector_type(16))) float f32x16;

static __device__ __forceinline__ uint16_t f2b(float f) {
  uint32_t u = __builtin_bit_cast(uint32_t, f);
  u += 0x7fffu + ((u >> 16) & 1u);
  return (uint16_t)(u >> 16);
}
static __device__ __forceinline__ float b2f(uint16_t b) {
  uint32_t u = ((uint32_t)b) << 16;
  return __builtin_bit_cast(float, u);
}

typedef const __attribute__((address_space(1))) uint32_t* gas_p;
typedef __attribute__((address_space(3))) uint32_t* las_p;
static __device__ __forceinline__ void gload16(const void* g, void* l) {
  __builtin_amdgcn_global_load_lds((gas_p)g, (las_p)l, 16, 0, 0);
}

// ------------- prep: castk (blocks 0..4095) + 4 weight transposes -------------
__global__ __launch_bounds__(256) void prep(const float* __restrict__ hidden,
                                            uint16_t* __restrict__ Xb,
                                            const float* __restrict__ Wq,
                                            const float* __restrict__ Wk,
                                            const float* __restrict__ Wv,
                                            const float* __restrict__ Wo,
                                            uint16_t* __restrict__ Wqt,
                                            uint16_t* __restrict__ Wkt,
                                            uint16_t* __restrict__ Wvt,
                                            uint16_t* __restrict__ Wot) {
  __shared__ float tt[32][33];
  int bid = blockIdx.x;
  if (bid < 4096) {
    int i = bid * 256 + threadIdx.x;
    float4 f = ((const float4*)hidden)[i];
    uint2 o;
    o.x = (uint32_t)f2b(f.x) | ((uint32_t)f2b(f.y) << 16);
    o.y = (uint32_t)f2b(f.z) | ((uint32_t)f2b(f.w) << 16);
    ((uint2*)Xb)[i] = o;
    return;
  }
  bid -= 4096;
  const float* src; uint16_t* dst; int K, N, bx, by;
  if (bid < 2048)       { src = Wq; dst = Wqt; K = 1024; N = 2048; bx = bid & 63; by = bid >> 6; }
  else if (bid < 3072)  { bid -= 2048; src = Wk; dst = Wkt; K = 1024; N = 1024; bx = bid & 31; by = bid >> 5; }
  else if (bid < 4096)  { bid -= 3072; src = Wv; dst = Wvt; K = 1024; N = 1024; bx = bid & 31; by = bid >> 5; }
  else                  { bid -= 4096; src = Wo; dst = Wot; K = 2048; N = 1024; bx = bid & 31; by = bid >> 5; }
  int nb = bx * 32, kb = by * 32;
  int tx = threadIdx.x & 31, ty = threadIdx.x >> 5;
  #pragma unroll
  for (int i = ty; i < 32; i += 8) tt[i][tx] = src[(size_t)(kb + i) * N + nb + tx];
  __syncthreads();
  #pragma unroll
  for (int i = ty; i < 32; i += 8) dst[(size_t)(nb + i) * K + kb + tx] = f2b(tt[tx][i]);
}

// ------------- fused QKV GEMM with norm/rope epilogue -------------
__global__ __launch_bounds__(256) void gemm_qkv(const uint16_t* __restrict__ A,
                                                const uint16_t* __restrict__ Bt,
                                                uint16_t* __restrict__ Qb,
                                                uint16_t* __restrict__ Kb,
                                                uint16_t* __restrict__ Vtb,
                                                const float* __restrict__ qw,
                                                const float* __restrict__ kw,
                                                const float* __restrict__ cosr,
                                                const float* __restrict__ sinr) {
  __shared__ uint16_t Sh[128 * 128];
  uint16_t* Al = Sh;
  uint16_t* Bl = Sh + 128 * 64;
  int tid = threadIdx.x;
  int lane = tid & 63, lr = lane & 15, g = lane >> 4;
  int w = tid >> 6, wm = w >> 1, wn = w & 1;
  int wbase = w * 64;
  int m0 = blockIdx.y * 128, n0 = blockIdx.x * 128;
  f32x4 acc[4][4] = {};
  for (int k0 = 0; k0 < 1024; k0 += 64) {
    __syncthreads();
    #pragma unroll
    for (int p = 0; p < 4; ++p) {
      int c = tid + p * 256;
      int row = c >> 3, cb = c & 7;
      int sc = (cb ^ (row & 7)) * 8;
      gload16(A + (size_t)(m0 + row) * 1024 + k0 + sc, Al + (size_t)(p * 256 + wbase) * 8);
      gload16(Bt + (size_t)(n0 + row) * 1024 + k0 + sc, Bl + (size_t)(p * 256 + wbase) * 8);
    }
    __syncthreads();
    #pragma unroll
    for (int ks = 0; ks < 2; ++ks) {
      bf16x8 af[4], bfr[4];
      #pragma unroll
      for (int mi = 0; mi < 4; ++mi) {
        int row = wm * 64 + mi * 16 + lr;
        af[mi] = *(bf16x8*)((char*)Al + row * 128 + ((ks * 64 + g * 16) ^ ((row & 7) << 4)));
      }
      #pragma unroll
      for (int ni = 0; ni < 4; ++ni) {
        int row = wn * 64 + ni * 16 + lr;
        bfr[ni] = *(bf16x8*)((char*)Bl + row * 128 + ((ks * 64 + g * 16) ^ ((row & 7) << 4)));
      }
      __builtin_amdgcn_s_setprio(1);
      #pragma unroll
      for (int mi = 0; mi < 4; ++mi)
        #pragma unroll
        for (int ni = 0; ni < 4; ++ni)
          acc[mi][ni] = __builtin_amdgcn_mfma_f32_16x16x32_bf16(af[mi], bfr[ni], acc[mi][ni], 0, 0, 0);
      __builtin_amdgcn_s_setprio(0);
    }
  }
  __syncthreads();
  uint16_t* L = Sh;
  #pragma unroll
  for (int mi = 0; mi < 4; ++mi)
    #pragma unroll
    for (int ni = 0; ni < 4; ++ni)
      #pragma unroll
      for (int e = 0; e < 4; ++e) {
        int row = wm * 64 + mi * 16 + 4 * g + e;
        int col = wn * 64 + ni * 16 + lr;
        L[row * 128 + ((((col >> 3) ^ (row & 7)) << 3) | (col & 7))] = f2b(acc[mi][ni][e]);
      }
  __syncthreads();
  int hsel = n0 >> 7;
  if (hsel < 24) {
    int row = tid >> 1, half = tid & 1;
    int gr = m0 + row, bb = gr >> 11, s = gr & 2047;
    int d0 = half * 32;
    float x[64];
    #pragma unroll
    for (int c8 = 0; c8 < 8; ++c8) {
      int jj = (c8 & 3) * 8 + d0 + (c8 >> 2) * 64;
      union { bf16x8 v; uint16_t u[8]; } tmp;
      tmp.v = *(bf16x8*)(L + row * 128 + (((jj >> 3) ^ (row & 7)) << 3));
      #pragma unroll
      for (int k = 0; k < 8; ++k) x[c8 * 8 + k] = b2f(tmp.u[k]);
    }
    float ss = 0.f;
    #pragma unroll
    for (int k = 0; k < 64; ++k) ss += x[k] * x[k];
    ss += __shfl_xor(ss, 1, 64);
    float rn = rsqrtf(ss * (1.0f / 128.0f) + EPS_);
    const float* wv = (hsel < 16) ? qw : kw;
    float scq = (hsel < 16) ? SCALE_ : 1.0f;
    rn *= scq;
    uint16_t* outp = (hsel < 16)
      ? Qb + (((size_t)(bb * 16 + hsel)) * 2048 + s) * 128
      : Kb + (((size_t)(bb * 8 + (hsel - 16))) * 2048 + s) * 128;
    const float* cR = cosr + s * 128;
    const float* sR = sinr + s * 128;
    #pragma unroll
    for (int c = 0; c < 4; ++c) {
      int dlo = d0 + c * 8;
      uint16_t olo[8], ohi[8];
      #pragma unroll
      for (int k = 0; k < 8; ++k) {
        int d = dlo + k;
        float x1 = x[c * 8 + k] * rn * wv[d];
        float x2 = x[32 + c * 8 + k] * rn * wv[d + 64];
        olo[k] = f2b(x1 * cR[d] - x2 * sR[d]);
        ohi[k] = f2b(x2 * cR[d + 64] + x1 * sR[d + 64]);
      }
      *(uint4*)(outp + dlo) = *(uint4*)olo;
      *(uint4*)(outp + 64 + dlo) = *(uint4*)ohi;
    }
  } else {
    int kvh = hsel - 24;
    int d0 = tid >> 1, sh = tid & 1;
    int bb = m0 >> 11, sg0 = (m0 & 2047) + sh * 64;
    union { uint16_t u[64]; uint4 q[8]; } vv;
    #pragma unroll
    for (int sl = 0; sl < 64; ++sl) {
      int srow = sh * 64 + sl;
      vv.u[sl] = L[srow * 128 + ((((d0 >> 3) ^ (srow & 7)) << 3) | (d0 & 7))];
    }
    uint16_t* vt = Vtb + (((size_t)(bb * 8 + kvh)) * 128 + d0) * 2048 + sg0;
    #pragma unroll
    for (int c = 0; c < 8; ++c) *(uint4*)(vt + c * 8) = vv.q[c];
  }
}

// ------------- Vt[bkv][d][s] -> packed Vp[bkv][kb64][dt*4+j][lane][8] -------------
__global__ __launch_bounds__(256) void vrepack(const uint16_t* __restrict__ Vt,
                                               uint16_t* __restrict__ Vp) {
  int bkv = blockIdx.y, p = blockIdx.x;
  const uint16_t* src = Vt + (size_t)bkv * KVSTRIDE_;
  uint16_t* dst = Vp + (size_t)bkv * KVSTRIDE_;
  #pragma unroll
  for (int i = 0; i < 16; ++i) {
    int idx = i * 256 + threadIdx.x;
    int d = idx >> 5, sc = p * 32 + (idx & 31);
    int s8 = sc * 8;
    uint4 v = *(const uint4*)(src + (size_t)d * 2048 + s8);
    int kb64 = s8 >> 6, j = (s8 >> 4) & 3, hh = (s8 >> 3) & 1;
    int dt = d >> 5, qlv = d & 31;
    ((uint4*)dst)[(kb64 * 16 + dt * 4 + j) * 64 + hh * 32 + qlv] = v;
  }
}

// ------------- GEMM BM=128, BN=64 (f32 out) for the O-projection -------------
__global__ __launch_bounds__(256) void gemm_o(const uint16_t* __restrict__ A,
                                              const uint16_t* __restrict__ Bt,
                                              float* __restrict__ Cout,
                                              int M, int N, int K) {
  __shared__ uint16_t Al[128 * 64];
  __shared__ uint16_t Bl[64 * 64];
  int tid = threadIdx.x;
  int lane = tid & 63, lr = lane & 15, g = lane >> 4;
  int w = tid >> 6, wm = w >> 1, wn = w & 1;
  int wbase = w * 64;
  int m0 = blockIdx.y * 128, n0 = blockIdx.x * 64;
  f32x4 acc[4][2] = {};
  for (int k0 = 0; k0 < K; k0 += 64) {
    __syncthreads();
    #pragma unroll
    for (int p = 0; p < 4; ++p) {
      int c = tid + p * 256;
      int row = c >> 3, cb = c & 7;
      int sc = (cb ^ (row & 7)) * 8;
      gload16(A + (size_t)(m0 + row) * K + k0 + sc, Al + (size_t)(p * 256 + wbase) * 8);
    }
    #pragma unroll
    for (int p = 0; p < 2; ++p) {
      int c = tid + p * 256;
      int row = c >> 3, cb = c & 7;
      int sc = (cb ^ (row & 7)) * 8;
      gload16(Bt + (size_t)(n0 + row) * K + k0 + sc, Bl + (size_t)(p * 256 + wbase) * 8);
    }
    __syncthreads();
    #pragma unroll
    for (int ks = 0; ks < 2; ++ks) {
      bf16x8 af[4], bfr[2];
      #pragma unroll
      for (int mi = 0; mi < 4; ++mi) {
        int row = wm * 64 + mi * 16 + lr;
        af[mi] = *(bf16x8*)((char*)Al + row * 128 + ((ks * 64 + g * 16) ^ ((row & 7) << 4)));
      }
      #pragma unroll
      for (int ni = 0; ni < 2; ++ni) {
        int row = wn * 32 + ni * 16 + lr;
        bfr[ni] = *(bf16x8*)((char*)Bl + row * 128 + ((ks * 64 + g * 16) ^ ((row & 7) << 4)));
      }
      __builtin_amdgcn_s_setprio(1);
      #pragma unroll
      for (int mi = 0; mi < 4; ++mi)
        #pragma unroll
        for (int ni = 0; ni < 2; ++ni)
          acc[mi][ni] = __builtin_amdgcn_mfma_f32_16x16x32_bf16(af[mi], bfr[ni], acc[mi][ni], 0, 0, 0);
      __builtin_amdgcn_s_setprio(0);
    }
  }
  #pragma unroll
  for (int mi = 0; mi < 4; ++mi)
    #pragma unroll
    for (int ni = 0; ni < 2; ++ni)
      #pragma unroll
      for (int e = 0; e < 4; ++e) {
        int row = m0 + wm * 64 + mi * 16 + 4 * g + e;
        int col = n0 + wn * 32 + ni * 16 + lr;
        Cout[(size_t)row * N + col] = acc[mi][ni][e];
      }
}

// ------------- causal GQA flash attention: in-block KV-split, KVBLK=32 -------------
// Block = 4 waves: (w&1) -> q-tile (qt = 2p + (w&1)), (w>>1) -> KV-half.
// Low half: kb in [0, p+1); high half: kb in [p+1, qt]. Uniform p+1 iterations.
// Two K streams staged per iter; partials merged via LDS at the end.
#define STAGE2(BUF, ITN) {                                                       \
  int klo = (ITN); int khi = nlow + (ITN);                                       \
  _Pragma("unroll") for (int p2 = 0; p2 < 4; ++p2) {                             \
    int stream = p2 >> 1;                                                        \
    int ci = (p2 & 1) * 4 + w;                                                   \
    int row = ci * 4 + (lane >> 4);                                              \
    int kg = (lane & 15) ^ (row & 7);                                            \
    int kb = stream ? khi : klo;                                                 \
    gload16(Kg + (size_t)(kb * 32 + row) * D_ + kg * 8,                          \
            (uint16_t*)smem + ((BUF) * 2 + stream) * 4096 + ci * 512);           \
  } }

__global__ __launch_bounds__(256, 4) void attn_kernel(const uint16_t* __restrict__ Qb,
                                                      const uint16_t* __restrict__ Kb,
                                                      const uint16_t* __restrict__ Vp,
                                                      uint16_t* __restrict__ out) {
  __shared__ __attribute__((aligned(16))) uint8_t smem[33280];
  int tid = threadIdx.x, lane = tid & 63, w = tid >> 6;
  int ql = lane & 31, hi = lane >> 5;
  int bi = blockIdx.x;
  int pr = 31 - (bi >> 5);            // longest pairs first
  int rem = bi & 31;
  int bkv = rem >> 1, hsel = rem & 1;
  int b = bkv >> 3, kv = bkv & 7, h = kv * 2 + hsel;
  int qt = pr * 2 + (w & 1);
  int half = w >> 1;
  int q0 = qt * 32;
  int nlow = pr + 1;
  const uint16_t* Qg = Qb + ((size_t)(b * H_ + h)) * S_ * D_;
  const uint16_t* Kg = Kb + ((size_t)(b * HKV_ + kv)) * S_ * D_;
  const uint16_t* Vpg = Vp + (size_t)(b * HKV_ + kv) * KVSTRIDE_;
  bf16x8 qf[8];
  #pragma unroll
  for (int t = 0; t < 8; ++t)
    qf[t] = *(const bf16x8*)(Qg + (size_t)(q0 + ql) * D_ + t * 16 + 8 * hi);
  f32x16 O[4] = {};
  float mrun = -__builtin_inff();
  float lrun = 0.f;
  STAGE2(0, 0)
  for (int it = 0; it <= pr; ++it) {
    int cur = it & 1;
    __syncthreads();                  // both streams of buf[cur] staged
    if (it < pr) STAGE2(cur ^ 1, it + 1)
    int kb = half ? nlow + it : it;
    if (!half || kb <= qt) {
      const uint16_t* KlC = (const uint16_t*)smem + (cur * 2 + half) * 4096;
      const uint16_t* Vb64 = Vpg + (size_t)(kb >> 1) * 8192;
      int j0 = (kb & 1) * 2;
      bool diag = (kb == qt);
      // ---- QK^T (32 keys, K from LDS) ----
      float p0[16];
      {
        bf16x8 kf[8];
        #pragma unroll
        for (int t = 0; t < 8; ++t)
          kf[t] = *(const bf16x8*)(KlC + ql * 128 + (((2 * t + hi) ^ (ql & 7)) * 8));
        f32x16 acc = {};
        __builtin_amdgcn_s_setprio(1);
        #pragma unroll
        for (int t = 0; t < 8; ++t)
          acc = __builtin_amdgcn_mfma_f32_32x32x16_bf16(kf[t], qf[t], acc, 0, 0, 0);
        __builtin_amdgcn_s_setprio(0);
        #pragma unroll
        for (int r = 0; r < 16; ++r) p0[r] = acc[r];
      }
      // ---- V fragments (early issue; latency hides under softmax) ----
      bf16x8 vf0[4], vf1[4];
      #pragma unroll
      for (int dt = 0; dt < 4; ++dt) {
        vf0[dt] = *(const bf16x8*)(Vb64 + ((dt * 4 + j0 + 0) * 64 + lane) * 8);
        vf1[dt] = *(const bf16x8*)(Vb64 + ((dt * 4 + j0 + 1) * 64 + lane) * 8);
      }
      // ---- causal mask on diagonal block ----
      if (diag) {
        #pragma unroll
        for (int r = 0; r < 16; ++r) {
          int kk = kb * 32 + 8 * (r >> 2) + 4 * hi + (r & 3);
          if (kk > q0 + ql) p0[r] = -__builtin_inff();
        }
      }
      // ---- max / deferred rescale ----
      float m8[8];
      #pragma unroll
      for (int i = 0; i < 8; ++i) m8[i] = fmaxf(p0[i], p0[i + 8]);
      float m4a = fmaxf(m8[0], m8[4]), m4b = fmaxf(m8[1], m8[5]);
      float m4c = fmaxf(m8[2], m8[6]), m4d = fmaxf(m8[3], m8[7]);
      float pmax = fmaxf(fmaxf(m4a, m4b), fmaxf(m4c, m4d));
      pmax = fmaxf(pmax, __shfl_xor(pmax, 32, 64));
      if (__any(pmax > mrun + 8.f)) {
        float mnew = fmaxf(mrun, pmax);
        float rs = __expf(mrun - mnew);
        lrun *= rs;
        #pragma unroll
        for (int r = 0; r < 16; ++r) {
          float rr = __shfl(rs, (r & 3) + 8 * (r >> 2) + 4 * hi, 64);
          #pragma unroll
          for (int dt = 0; dt < 4; ++dt) O[dt][r] *= rr;
        }
        mrun = mnew;
      }
      float ls = 0.f;
      #pragma unroll
      for (int r = 0; r < 16; ++r) { p0[r] = __expf(p0[r] - mrun); ls += p0[r]; }
      // ---- pack P -> bf16 A-frags ----
      union PW { uint32_t w[4]; bf16x8 v; } pa0, pa1;
      {
        uint32_t uu[4][2];
        #pragma unroll
        for (int T = 0; T < 4; ++T) {
          asm("v_cvt_pk_bf16_f32 %0, %1, %2" : "=v"(uu[T][0]) : "v"(p0[4 * T]), "v"(p0[4 * T + 1]));
          asm("v_cvt_pk_bf16_f32 %0, %1, %2" : "=v"(uu[T][1]) : "v"(p0[4 * T + 2]), "v"(p0[4 * T + 3]));
        }
        uint32_t a = uu[0][0], bb2 = uu[1][0];
        asm("v_permlane32_swap_b32 %0, %1" : "+v"(a), "+v"(bb2));
        uint32_t c = uu[0][1], d = uu[1][1];
        asm("v_permlane32_swap_b32 %0, %1" : "+v"(c), "+v"(d));
        pa0.w[0] = a; pa0.w[1] = c; pa0.w[2] = bb2; pa0.w[3] = d;
        uint32_t a2 = uu[2][0], b2 = uu[3][0];
        asm("v_permlane32_swap_b32 %0, %1" : "+v"(a2), "+v"(b2));
        uint32_t c2 = uu[2][1], d2 = uu[3][1];
        asm("v_permlane32_swap_b32 %0, %1" : "+v"(c2), "+v"(d2));
        pa1.w[0] = a2; pa1.w[1] = c2; pa1.w[2] = b2; pa1.w[3] = d2;
      }
      __builtin_amdgcn_s_setprio(1);
      #pragma unroll
      for (int dt = 0; dt < 4; ++dt) {
        O[dt] = __builtin_amdgcn_mfma_f32_32x32x16_bf16(pa0.v, vf0[dt], O[dt], 0, 0, 0);
        O[dt] = __builtin_amdgcn_mfma_f32_32x32x16_bf16(pa1.v, vf1[dt], O[dt], 0, 0, 0);
      }
      __builtin_amdgcn_s_setprio(0);
      ls += __shfl_xor(ls, 32, 64);
      lrun += ls;
    }
  }
  // ---- merge partials across KV-halves (w0<-w2 for qtA, w1<-w3 for qtB) ----
  __syncthreads();                    // all K reads done; smem reusable
  float* Om = (float*)smem;           // [2][32][128]
  float* Ml = (float*)(smem + 32768); // [2][32][2]
  int slot = w & 1;
  if (half) {
    #pragma unroll
    for (int r = 0; r < 16; ++r) {
      int qrl = (r & 3) + 8 * (r >> 2) + 4 * hi;
      #pragma unroll
      for (int dt = 0; dt < 4; ++dt)
        Om[slot * 4096 + qrl * 128 + dt * 32 + ql] = O[dt][r];
    }
    if (hi == 0) { Ml[slot * 64 + ql * 2] = mrun; Ml[slot * 64 + ql * 2 + 1] = lrun; }
  }
  __syncthreads();
  if (!half) {
    float m2 = Ml[slot * 64 + ql * 2], l2 = Ml[slot * 64 + ql * 2 + 1];
    float mn = fmaxf(mrun, m2);
    float a1 = __expf(mrun - mn), a2 = __expf(m2 - mn);
    float lfin = lrun * a1 + l2 * a2;
    float linv = 1.0f / lfin;
    #pragma unroll
    for (int r = 0; r < 16; ++r) {
      int qrl = (r & 3) + 8 * (r >> 2) + 4 * hi;
      float a1r = __shfl(a1, qrl, 64);
      float a2r = __shfl(a2, qrl, 64);
      float lr_ = __shfl(linv, qrl, 64);
      #pragma unroll
      for (int dt = 0; dt < 4; ++dt) {
        float v = O[dt][r] * a1r + Om[slot * 4096 + qrl * 128 + dt * 32 + ql] * a2r;
        out[((size_t)(b * S_ + q0 + qrl)) * 2048 + h * 128 + dt * 32 + ql] = f2b(v * lr_);
      }
    }
  }
}

extern "C" void kernel_launch(void* const* d_in, const int* in_sizes, int n_in,
                              void* d_out, int out_size, void* d_ws, size_t ws_size,
                              hipStream_t stream) {
  const float* hidden = (const float*)d_in[0];
  const float* cosr = (const float*)d_in[2];
  const float* sinr = (const float*)d_in[3];
  const float* Wq = (const float*)d_in[4];
  const float* Wk = (const float*)d_in[5];
  const float* Wv = (const float*)d_in[6];
  const float* Wo = (const float*)d_in[7];
  const float* qw = (const float*)d_in[8];
  const float* kw = (const float*)d_in[9];

  uint16_t* p = (uint16_t*)d_ws;
  uint16_t* Xb   = p; p += (size_t)4096 * 1024;
  uint16_t* Wqt  = p; p += (size_t)2048 * 1024;   // Wqt|Wkt|Wvt contiguous fused B^T
  uint16_t* Wkt  = p; p += (size_t)1024 * 1024;
  uint16_t* Wvt  = p; p += (size_t)1024 * 1024;
  uint16_t* Wot  = p; p += (size_t)1024 * 2048;
  uint16_t* Qbuf = p; p += (size_t)B_ * H_ * S_ * D_;
  uint16_t* Kbuf = p; p += (size_t)B_ * HKV_ * S_ * D_;
  uint16_t* Vtb  = p; p += (size_t)B_ * HKV_ * S_ * D_;   // V^T [bkv][128][2048]
  uint16_t* attn = p; p += (size_t)4096 * 2048;
  uint16_t* Vpb  = Xb;  // packed V fragments; aliases Xb (dead after gemm_qkv)

  prep<<<10240, 256, 0, stream>>>(hidden, Xb, Wq, Wk, Wv, Wo, Wqt, Wkt, Wvt, Wot);
  gemm_qkv<<<dim3(32, 32), 256, 0, stream>>>(Xb, Wqt, Qbuf, Kbuf, Vtb, qw, kw, cosr, sinr);
  vrepack<<<dim3(8, 16), 256, 0, stream>>>(Vtb, Vpb);
  attn_kernel<<<1024, 256, 0, stream>>>(Qbuf, Kbuf, Vpb, attn);
  gemm_o<<<dim3(16, 32), 256, 0, stream>>>(attn, Wot, (float*)d_out, 4096, 1024, 2048);
}

// Round 15
// 208.818 us; speedup vs baseline: 1.8395x; 1.8395x over previous
//
#include <hip/hip_runtime.h>
#include <stdint.h>

#define B_ 2
#define S_ 2048
#define H_ 16
#define HKV_ 8
#define D_ 128
#define EPS_ 1e-6f
#define SCALE_ 0.08838834764831845f
#define KVSTRIDE_ 262144   // per (b,kv): 2048*128 elems

typedef __attribute__((ext_vector_type(8))) __bf16 bf16x8;
typedef __attribute__((ext_vector_type(4))) float f32x4;
typedef __attribute__((ext_vector_type(16))) float f32x16;

static __device__ __forceinline__ uint16_t f2b(float f) {
  uint32_t u = __builtin_bit_cast(uint32_t, f);
  u += 0x7fffu + ((u >> 16) & 1u);
  return (uint16_t)(u >> 16);
}
static __device__ __forceinline__ float b2f(uint16_t b) {
  uint32_t u = ((uint32_t)b) << 16;
  return __builtin_bit_cast(float, u);
}

typedef const __attribute__((address_space(1))) uint32_t* gas_p;
typedef __attribute__((address_space(3))) uint32_t* las_p;
static __device__ __forceinline__ void gload16(const void* g, void* l) {
  __builtin_amdgcn_global_load_lds((gas_p)g, (las_p)l, 16, 0, 0);
}

// ------------- prep: castk (blocks 0..4095) + 4 weight transposes -------------
__global__ __launch_bounds__(256) void prep(const float* __restrict__ hidden,
                                            uint16_t* __restrict__ Xb,
                                            const float* __restrict__ Wq,
                                            const float* __restrict__ Wk,
                                            const float* __restrict__ Wv,
                                            const float* __restrict__ Wo,
                                            uint16_t* __restrict__ Wqt,
                                            uint16_t* __restrict__ Wkt,
                                            uint16_t* __restrict__ Wvt,
                                            uint16_t* __restrict__ Wot) {
  __shared__ float tt[32][33];
  int bid = blockIdx.x;
  if (bid < 4096) {
    int i = bid * 256 + threadIdx.x;
    float4 f = ((const float4*)hidden)[i];
    uint2 o;
    o.x = (uint32_t)f2b(f.x) | ((uint32_t)f2b(f.y) << 16);
    o.y = (uint32_t)f2b(f.z) | ((uint32_t)f2b(f.w) << 16);
    ((uint2*)Xb)[i] = o;
    return;
  }
  bid -= 4096;
  const float* src; uint16_t* dst; int K, N, bx, by;
  if (bid < 2048)       { src = Wq; dst = Wqt; K = 1024; N = 2048; bx = bid & 63; by = bid >> 6; }
  else if (bid < 3072)  { bid -= 2048; src = Wk; dst = Wkt; K = 1024; N = 1024; bx = bid & 31; by = bid >> 5; }
  else if (bid < 4096)  { bid -= 3072; src = Wv; dst = Wvt; K = 1024; N = 1024; bx = bid & 31; by = bid >> 5; }
  else                  { bid -= 4096; src = Wo; dst = Wot; K = 2048; N = 1024; bx = bid & 31; by = bid >> 5; }
  int nb = bx * 32, kb = by * 32;
  int tx = threadIdx.x & 31, ty = threadIdx.x >> 5;
  #pragma unroll
  for (int i = ty; i < 32; i += 8) tt[i][tx] = src[(size_t)(kb + i) * N + nb + tx];
  __syncthreads();
  #pragma unroll
  for (int i = ty; i < 32; i += 8) dst[(size_t)(nb + i) * K + kb + tx] = f2b(tt[tx][i]);
}

// ------------- fused QKV GEMM with norm/rope epilogue -------------
__global__ __launch_bounds__(256) void gemm_qkv(const uint16_t* __restrict__ A,
                                                const uint16_t* __restrict__ Bt,
                                                uint16_t* __restrict__ Qb,
                                                uint16_t* __restrict__ Kb,
                                                uint16_t* __restrict__ Vtb,
                                                const float* __restrict__ qw,
                                                const float* __restrict__ kw,
                                                const float* __restrict__ cosr,
                                                const float* __restrict__ sinr) {
  __shared__ uint16_t Sh[128 * 128];
  uint16_t* Al = Sh;
  uint16_t* Bl = Sh + 128 * 64;
  int tid = threadIdx.x;
  int lane = tid & 63, lr = lane & 15, g = lane >> 4;
  int w = tid >> 6, wm = w >> 1, wn = w & 1;
  int wbase = w * 64;
  int m0 = blockIdx.y * 128, n0 = blockIdx.x * 128;
  f32x4 acc[4][4] = {};
  for (int k0 = 0; k0 < 1024; k0 += 64) {
    __syncthreads();
    #pragma unroll
    for (int p = 0; p < 4; ++p) {
      int c = tid + p * 256;
      int row = c >> 3, cb = c & 7;
      int sc = (cb ^ (row & 7)) * 8;
      gload16(A + (size_t)(m0 + row) * 1024 + k0 + sc, Al + (size_t)(p * 256 + wbase) * 8);
      gload16(Bt + (size_t)(n0 + row) * 1024 + k0 + sc, Bl + (size_t)(p * 256 + wbase) * 8);
    }
    __syncthreads();
    #pragma unroll
    for (int ks = 0; ks < 2; ++ks) {
      bf16x8 af[4], bfr[4];
      #pragma unroll
      for (int mi = 0; mi < 4; ++mi) {
        int row = wm * 64 + mi * 16 + lr;
        af[mi] = *(bf16x8*)((char*)Al + row * 128 + ((ks * 64 + g * 16) ^ ((row & 7) << 4)));
      }
      #pragma unroll
      for (int ni = 0; ni < 4; ++ni) {
        int row = wn * 64 + ni * 16 + lr;
        bfr[ni] = *(bf16x8*)((char*)Bl + row * 128 + ((ks * 64 + g * 16) ^ ((row & 7) << 4)));
      }
      __builtin_amdgcn_s_setprio(1);
      #pragma unroll
      for (int mi = 0; mi < 4; ++mi)
        #pragma unroll
        for (int ni = 0; ni < 4; ++ni)
          acc[mi][ni] = __builtin_amdgcn_mfma_f32_16x16x32_bf16(af[mi], bfr[ni], acc[mi][ni], 0, 0, 0);
      __builtin_amdgcn_s_setprio(0);
    }
  }
  __syncthreads();
  uint16_t* L = Sh;
  #pragma unroll
  for (int mi = 0; mi < 4; ++mi)
    #pragma unroll
    for (int ni = 0; ni < 4; ++ni)
      #pragma unroll
      for (int e = 0; e < 4; ++e) {
        int row = wm * 64 + mi * 16 + 4 * g + e;
        int col = wn * 64 + ni * 16 + lr;
        L[row * 128 + ((((col >> 3) ^ (row & 7)) << 3) | (col & 7))] = f2b(acc[mi][ni][e]);
      }
  __syncthreads();
  int hsel = n0 >> 7;
  if (hsel < 24) {
    int row = tid >> 1, half = tid & 1;
    int gr = m0 + row, bb = gr >> 11, s = gr & 2047;
    int d0 = half * 32;
    float x[64];
    #pragma unroll
    for (int c8 = 0; c8 < 8; ++c8) {
      int jj = (c8 & 3) * 8 + d0 + (c8 >> 2) * 64;
      union { bf16x8 v; uint16_t u[8]; } tmp;
      tmp.v = *(bf16x8*)(L + row * 128 + (((jj >> 3) ^ (row & 7)) << 3));
      #pragma unroll
      for (int k = 0; k < 8; ++k) x[c8 * 8 + k] = b2f(tmp.u[k]);
    }
    float ss = 0.f;
    #pragma unroll
    for (int k = 0; k < 64; ++k) ss += x[k] * x[k];
    ss += __shfl_xor(ss, 1, 64);
    float rn = rsqrtf(ss * (1.0f / 128.0f) + EPS_);
    const float* wv = (hsel < 16) ? qw : kw;
    float scq = (hsel < 16) ? SCALE_ : 1.0f;
    rn *= scq;
    uint16_t* outp = (hsel < 16)
      ? Qb + (((size_t)(bb * 16 + hsel)) * 2048 + s) * 128
      : Kb + (((size_t)(bb * 8 + (hsel - 16))) * 2048 + s) * 128;
    const float* cR = cosr + s * 128;
    const float* sR = sinr + s * 128;
    #pragma unroll
    for (int c = 0; c < 4; ++c) {
      int dlo = d0 + c * 8;
      uint16_t olo[8], ohi[8];
      #pragma unroll
      for (int k = 0; k < 8; ++k) {
        int d = dlo + k;
        float x1 = x[c * 8 + k] * rn * wv[d];
        float x2 = x[32 + c * 8 + k] * rn * wv[d + 64];
        olo[k] = f2b(x1 * cR[d] - x2 * sR[d]);
        ohi[k] = f2b(x2 * cR[d + 64] + x1 * sR[d + 64]);
      }
      *(uint4*)(outp + dlo) = *(uint4*)olo;
      *(uint4*)(outp + 64 + dlo) = *(uint4*)ohi;
    }
  } else {
    int kvh = hsel - 24;
    int d0 = tid >> 1, sh = tid & 1;
    int bb = m0 >> 11, sg0 = (m0 & 2047) + sh * 64;
    union { uint16_t u[64]; uint4 q[8]; } vv;
    #pragma unroll
    for (int sl = 0; sl < 64; ++sl) {
      int srow = sh * 64 + sl;
      vv.u[sl] = L[srow * 128 + ((((d0 >> 3) ^ (srow & 7)) << 3) | (d0 & 7))];
    }
    uint16_t* vt = Vtb + (((size_t)(bb * 8 + kvh)) * 128 + d0) * 2048 + sg0;
    #pragma unroll
    for (int c = 0; c < 8; ++c) *(uint4*)(vt + c * 8) = vv.q[c];
  }
}

// ------------- Vt[bkv][d][s] -> packed Vp[bkv][kb64][dt*4+j][lane][8] -------------
__global__ __launch_bounds__(256) void vrepack(const uint16_t* __restrict__ Vt,
                                               uint16_t* __restrict__ Vp) {
  int bkv = blockIdx.y, p = blockIdx.x;
  const uint16_t* src = Vt + (size_t)bkv * KVSTRIDE_;
  uint16_t* dst = Vp + (size_t)bkv * KVSTRIDE_;
  #pragma unroll
  for (int i = 0; i < 16; ++i) {
    int idx = i * 256 + threadIdx.x;
    int d = idx >> 5, sc = p * 32 + (idx & 31);
    int s8 = sc * 8;
    uint4 v = *(const uint4*)(src + (size_t)d * 2048 + s8);
    int kb64 = s8 >> 6, j = (s8 >> 4) & 3, hh = (s8 >> 3) & 1;
    int dt = d >> 5, qlv = d & 31;
    ((uint4*)dst)[(kb64 * 16 + dt * 4 + j) * 64 + hh * 32 + qlv] = v;
  }
}

// ------------- GEMM BM=128, BN=64 (f32 out) for the O-projection -------------
__global__ __launch_bounds__(256) void gemm_o(const uint16_t* __restrict__ A,
                                              const uint16_t* __restrict__ Bt,
                                              float* __restrict__ Cout,
                                              int M, int N, int K) {
  __shared__ uint16_t Al[128 * 64];
  __shared__ uint16_t Bl[64 * 64];
  int tid = threadIdx.x;
  int lane = tid & 63, lr = lane & 15, g = lane >> 4;
  int w = tid >> 6, wm = w >> 1, wn = w & 1;
  int wbase = w * 64;
  int m0 = blockIdx.y * 128, n0 = blockIdx.x * 64;
  f32x4 acc[4][2] = {};
  for (int k0 = 0; k0 < K; k0 += 64) {
    __syncthreads();
    #pragma unroll
    for (int p = 0; p < 4; ++p) {
      int c = tid + p * 256;
      int row = c >> 3, cb = c & 7;
      int sc = (cb ^ (row & 7)) * 8;
      gload16(A + (size_t)(m0 + row) * K + k0 + sc, Al + (size_t)(p * 256 + wbase) * 8);
    }
    #pragma unroll
    for (int p = 0; p < 2; ++p) {
      int c = tid + p * 256;
      int row = c >> 3, cb = c & 7;
      int sc = (cb ^ (row & 7)) * 8;
      gload16(Bt + (size_t)(n0 + row) * K + k0 + sc, Bl + (size_t)(p * 256 + wbase) * 8);
    }
    __syncthreads();
    #pragma unroll
    for (int ks = 0; ks < 2; ++ks) {
      bf16x8 af[4], bfr[2];
      #pragma unroll
      for (int mi = 0; mi < 4; ++mi) {
        int row = wm * 64 + mi * 16 + lr;
        af[mi] = *(bf16x8*)((char*)Al + row * 128 + ((ks * 64 + g * 16) ^ ((row & 7) << 4)));
      }
      #pragma unroll
      for (int ni = 0; ni < 2; ++ni) {
        int row = wn * 32 + ni * 16 + lr;
        bfr[ni] = *(bf16x8*)((char*)Bl + row * 128 + ((ks * 64 + g * 16) ^ ((row & 7) << 4)));
      }
      __builtin_amdgcn_s_setprio(1);
      #pragma unroll
      for (int mi = 0; mi < 4; ++mi)
        #pragma unroll
        for (int ni = 0; ni < 2; ++ni)
          acc[mi][ni] = __builtin_amdgcn_mfma_f32_16x16x32_bf16(af[mi], bfr[ni], acc[mi][ni], 0, 0, 0);
      __builtin_amdgcn_s_setprio(0);
    }
  }
  #pragma unroll
  for (int mi = 0; mi < 4; ++mi)
    #pragma unroll
    for (int ni = 0; ni < 2; ++ni)
      #pragma unroll
      for (int e = 0; e < 4; ++e) {
        int row = m0 + wm * 64 + mi * 16 + 4 * g + e;
        int col = n0 + wn * 32 + ni * 16 + lr;
        Cout[(size_t)row * N + col] = acc[mi][ni][e];
      }
}

// ------------- causal GQA flash attention: in-block KV-split, KVBLK=32 -------------
// Block = 4 waves: (w&1) -> q-tile (qt = 2p + (w&1)), (w>>1) -> KV-half.
// Math verified R14 (passed); this round only relaxes the VGPR cap that
// caused wholesale accumulator spill (VGPR 64, 553MB scratch FETCH).
#define STAGE2(BUF, ITN) {                                                       \
  int klo = (ITN); int khi = nlow + (ITN);                                       \
  _Pragma("unroll") for (int p2 = 0; p2 < 4; ++p2) {                             \
    int stream = p2 >> 1;                                                        \
    int ci = (p2 & 1) * 4 + w;                                                   \
    int row = ci * 4 + (lane >> 4);                                              \
    int kg = (lane & 15) ^ (row & 7);                                            \
    int kb = stream ? khi : klo;                                                 \
    gload16(Kg + (size_t)(kb * 32 + row) * D_ + kg * 8,                          \
            (uint16_t*)smem + ((BUF) * 2 + stream) * 4096 + ci * 512);           \
  } }

__global__ __launch_bounds__(256) void attn_kernel(const uint16_t* __restrict__ Qb,
                                                   const uint16_t* __restrict__ Kb,
                                                   const uint16_t* __restrict__ Vp,
                                                   uint16_t* __restrict__ out) {
  __shared__ __attribute__((aligned(16))) uint8_t smem[33280];
  int tid = threadIdx.x, lane = tid & 63, w = tid >> 6;
  int ql = lane & 31, hi = lane >> 5;
  int bi = blockIdx.x;
  int pr = 31 - (bi >> 5);            // longest pairs first
  int rem = bi & 31;
  int bkv = rem >> 1, hsel = rem & 1;
  int b = bkv >> 3, kv = bkv & 7, h = kv * 2 + hsel;
  int qt = pr * 2 + (w & 1);
  int half = w >> 1;
  int q0 = qt * 32;
  int nlow = pr + 1;
  const uint16_t* Qg = Qb + ((size_t)(b * H_ + h)) * S_ * D_;
  const uint16_t* Kg = Kb + ((size_t)(b * HKV_ + kv)) * S_ * D_;
  const uint16_t* Vpg = Vp + (size_t)(b * HKV_ + kv) * KVSTRIDE_;
  bf16x8 qf[8];
  #pragma unroll
  for (int t = 0; t < 8; ++t)
    qf[t] = *(const bf16x8*)(Qg + (size_t)(q0 + ql) * D_ + t * 16 + 8 * hi);
  f32x16 O[4] = {};
  float mrun = -__builtin_inff();
  float lrun = 0.f;
  STAGE2(0, 0)
  for (int it = 0; it <= pr; ++it) {
    int cur = it & 1;
    __syncthreads();                  // both streams of buf[cur] staged
    if (it < pr) STAGE2(cur ^ 1, it + 1)
    int kb = half ? nlow + it : it;
    if (!half || kb <= qt) {
      const uint16_t* KlC = (const uint16_t*)smem + (cur * 2 + half) * 4096;
      const uint16_t* Vb64 = Vpg + (size_t)(kb >> 1) * 8192;
      int j0 = (kb & 1) * 2;
      bool diag = (kb == qt);
      // ---- QK^T (32 keys, K from LDS) ----
      float p0[16];
      {
        bf16x8 kf[8];
        #pragma unroll
        for (int t = 0; t < 8; ++t)
          kf[t] = *(const bf16x8*)(KlC + ql * 128 + (((2 * t + hi) ^ (ql & 7)) * 8));
        f32x16 acc = {};
        __builtin_amdgcn_s_setprio(1);
        #pragma unroll
        for (int t = 0; t < 8; ++t)
          acc = __builtin_amdgcn_mfma_f32_32x32x16_bf16(kf[t], qf[t], acc, 0, 0, 0);
        __builtin_amdgcn_s_setprio(0);
        #pragma unroll
        for (int r = 0; r < 16; ++r) p0[r] = acc[r];
      }
      // ---- V fragments (early issue; latency hides under softmax) ----
      bf16x8 vf0[4], vf1[4];
      #pragma unroll
      for (int dt = 0; dt < 4; ++dt) {
        vf0[dt] = *(const bf16x8*)(Vb64 + ((dt * 4 + j0 + 0) * 64 + lane) * 8);
        vf1[dt] = *(const bf16x8*)(Vb64 + ((dt * 4 + j0 + 1) * 64 + lane) * 8);
      }
      // ---- causal mask on diagonal block ----
      if (diag) {
        #pragma unroll
        for (int r = 0; r < 16; ++r) {
          int kk = kb * 32 + 8 * (r >> 2) + 4 * hi + (r & 3);
          if (kk > q0 + ql) p0[r] = -__builtin_inff();
        }
      }
      // ---- max / deferred rescale ----
      float m8[8];
      #pragma unroll
      for (int i = 0; i < 8; ++i) m8[i] = fmaxf(p0[i], p0[i + 8]);
      float m4a = fmaxf(m8[0], m8[4]), m4b = fmaxf(m8[1], m8[5]);
      float m4c = fmaxf(m8[2], m8[6]), m4d = fmaxf(m8[3], m8[7]);
      float pmax = fmaxf(fmaxf(m4a, m4b), fmaxf(m4c, m4d));
      pmax = fmaxf(pmax, __shfl_xor(pmax, 32, 64));
      if (__any(pmax > mrun + 8.f)) {
        float mnew = fmaxf(mrun, pmax);
        float rs = __expf(mrun - mnew);
        lrun *= rs;
        #pragma unroll
        for (int r = 0; r < 16; ++r) {
          float rr = __shfl(rs, (r & 3) + 8 * (r >> 2) + 4 * hi, 64);
          #pragma unroll
          for (int dt = 0; dt < 4; ++dt) O[dt][r] *= rr;
        }
        mrun = mnew;
      }
      float ls = 0.f;
      #pragma unroll
      for (int r = 0; r < 16; ++r) { p0[r] = __expf(p0[r] - mrun); ls += p0[r]; }
      // ---- pack P -> bf16 A-frags ----
      union PW { uint32_t w[4]; bf16x8 v; } pa0, pa1;
      {
        uint32_t uu[4][2];
        #pragma unroll
        for (int T = 0; T < 4; ++T) {
          asm("v_cvt_pk_bf16_f32 %0, %1, %2" : "=v"(uu[T][0]) : "v"(p0[4 * T]), "v"(p0[4 * T + 1]));
          asm("v_cvt_pk_bf16_f32 %0, %1, %2" : "=v"(uu[T][1]) : "v"(p0[4 * T + 2]), "v"(p0[4 * T + 3]));
        }
        uint32_t a = uu[0][0], bb2 = uu[1][0];
        asm("v_permlane32_swap_b32 %0, %1" : "+v"(a), "+v"(bb2));
        uint32_t c = uu[0][1], d = uu[1][1];
        asm("v_permlane32_swap_b32 %0, %1" : "+v"(c), "+v"(d));
        pa0.w[0] = a; pa0.w[1] = c; pa0.w[2] = bb2; pa0.w[3] = d;
        uint32_t a2 = uu[2][0], b2 = uu[3][0];
        asm("v_permlane32_swap_b32 %0, %1" : "+v"(a2), "+v"(b2));
        uint32_t c2 = uu[2][1], d2 = uu[3][1];
        asm("v_permlane32_swap_b32 %0, %1" : "+v"(c2), "+v"(d2));
        pa1.w[0] = a2; pa1.w[1] = c2; pa1.w[2] = b2; pa1.w[3] = d2;
      }
      __builtin_amdgcn_s_setprio(1);
      #pragma unroll
      for (int dt = 0; dt < 4; ++dt) {
        O[dt] = __builtin_amdgcn_mfma_f32_32x32x16_bf16(pa0.v, vf0[dt], O[dt], 0, 0, 0);
        O[dt] = __builtin_amdgcn_mfma_f32_32x32x16_bf16(pa1.v, vf1[dt], O[dt], 0, 0, 0);
      }
      __builtin_amdgcn_s_setprio(0);
      ls += __shfl_xor(ls, 32, 64);
      lrun += ls;
    }
  }
  // ---- merge partials across KV-halves (w0<-w2 for qtA, w1<-w3 for qtB) ----
  __syncthreads();                    // all K reads done; smem reusable
  float* Om = (float*)smem;           // [2][32][128]
  float* Ml = (float*)(smem + 32768); // [2][32][2]
  int slot = w & 1;
  if (half) {
    #pragma unroll
    for (int r = 0; r < 16; ++r) {
      int qrl = (r & 3) + 8 * (r >> 2) + 4 * hi;
      #pragma unroll
      for (int dt = 0; dt < 4; ++dt)
        Om[slot * 4096 + qrl * 128 + dt * 32 + ql] = O[dt][r];
    }
    if (hi == 0) { Ml[slot * 64 + ql * 2] = mrun; Ml[slot * 64 + ql * 2 + 1] = lrun; }
  }
  __syncthreads();
  if (!half) {
    float m2 = Ml[slot * 64 + ql * 2], l2 = Ml[slot * 64 + ql * 2 + 1];
    float mn = fmaxf(mrun, m2);
    float a1 = __expf(mrun - mn), a2 = __expf(m2 - mn);
    float lfin = lrun * a1 + l2 * a2;
    float linv = 1.0f / lfin;
    #pragma unroll
    for (int r = 0; r < 16; ++r) {
      int qrl = (r & 3) + 8 * (r >> 2) + 4 * hi;
      float a1r = __shfl(a1, qrl, 64);
      float a2r = __shfl(a2, qrl, 64);
      float lr_ = __shfl(linv, qrl, 64);
      #pragma unroll
      for (int dt = 0; dt < 4; ++dt) {
        float v = O[dt][r] * a1r + Om[slot * 4096 + qrl * 128 + dt * 32 + ql] * a2r;
        out[((size_t)(b * S_ + q0 + qrl)) * 2048 + h * 128 + dt * 32 + ql] = f2b(v * lr_);
      }
    }
  }
}

extern "C" void kernel_launch(void* const* d_in, const int* in_sizes, int n_in,
                              void* d_out, int out_size, void* d_ws, size_t ws_size,
                              hipStream_t stream) {
  const float* hidden = (const float*)d_in[0];
  const float* cosr = (const float*)d_in[2];
  const float* sinr = (const float*)d_in[3];
  const float* Wq = (const float*)d_in[4];
  const float* Wk = (const float*)d_in[5];
  const float* Wv = (const float*)d_in[6];
  const float* Wo = (const float*)d_in[7];
  const float* qw = (const float*)d_in[8];
  const float* kw = (const float*)d_in[9];

  uint16_t* p = (uint16_t*)d_ws;
  uint16_t* Xb   = p; p += (size_t)4096 * 1024;
  uint16_t* Wqt  = p; p += (size_t)2048 * 1024;   // Wqt|Wkt|Wvt contiguous fused B^T
  uint16_t* Wkt  = p; p += (size_t)1024 * 1024;
  uint16_t* Wvt  = p; p += (size_t)1024 * 1024;
  uint16_t* Wot  = p; p += (size_t)1024 * 2048;
  uint16_t* Qbuf = p; p += (size_t)B_ * H_ * S_ * D_;
  uint16_t* Kbuf = p; p += (size_t)B_ * HKV_ * S_ * D_;
  uint16_t* Vtb  = p; p += (size_t)B_ * HKV_ * S_ * D_;   // V^T [bkv][128][2048]
  uint16_t* attn = p; p += (size_t)4096 * 2048;
  uint16_t* Vpb  = Xb;  // packed V fragments; aliases Xb (dead after gemm_qkv)

  prep<<<10240, 256, 0, stream>>>(hidden, Xb, Wq, Wk, Wv, Wo, Wqt, Wkt, Wvt, Wot);
  gemm_qkv<<<dim3(32, 32), 256, 0, stream>>>(Xb, Wqt, Qbuf, Kbuf, Vtb, qw, kw, cosr, sinr);
  vrepack<<<dim3(8, 16), 256, 0, stream>>>(Vtb, Vpb);
  attn_kernel<<<1024, 256, 0, stream>>>(Qbuf, Kbuf, Vpb, attn);
  gemm_o<<<dim3(16, 32), 256, 0, stream>>>(attn, Wot, (float*)d_out, 4096, 1024, 2048);
}

// Round 16
// 175.407 us; speedup vs baseline: 2.1899x; 1.1905x over previous
//
#include <hip/hip_runtime.h>
#include <stdint.h>

#define B_ 2
#define S_ 2048
#define H_ 16
#define HKV_ 8
#define D_ 128
#define EPS_ 1e-6f
#define SCALE_ 0.08838834764831845f
#define KVSTRIDE_ 262144   // per (b,kv): 2048*128 elems

typedef __attribute__((ext_vector_type(8))) __bf16 bf16x8;
typedef __attribute__((ext_vector_type(4))) float f32x4;
typedef __attribute__((ext_vector_type(16))) float f32x16;

static __device__ __forceinline__ uint16_t f2b(float f) {
  uint32_t u = __builtin_bit_cast(uint32_t, f);
  u += 0x7fffu + ((u >> 16) & 1u);
  return (uint16_t)(u >> 16);
}
static __device__ __forceinline__ float b2f(uint16_t b) {
  uint32_t u = ((uint32_t)b) << 16;
  return __builtin_bit_cast(float, u);
}

typedef const __attribute__((address_space(1))) uint32_t* gas_p;
typedef __attribute__((address_space(3))) uint32_t* las_p;
static __device__ __forceinline__ void gload16(const void* g, void* l) {
  __builtin_amdgcn_global_load_lds((gas_p)g, (las_p)l, 16, 0, 0);
}

// ------------- prep: castk (blocks 0..4095) + 4 weight transposes -------------
__global__ __launch_bounds__(256) void prep(const float* __restrict__ hidden,
                                            uint16_t* __restrict__ Xb,
                                            const float* __restrict__ Wq,
                                            const float* __restrict__ Wk,
                                            const float* __restrict__ Wv,
                                            const float* __restrict__ Wo,
                                            uint16_t* __restrict__ Wqt,
                                            uint16_t* __restrict__ Wkt,
                                            uint16_t* __restrict__ Wvt,
                                            uint16_t* __restrict__ Wot) {
  __shared__ float tt[32][33];
  int bid = blockIdx.x;
  if (bid < 4096) {
    int i = bid * 256 + threadIdx.x;
    float4 f = ((const float4*)hidden)[i];
    uint2 o;
    o.x = (uint32_t)f2b(f.x) | ((uint32_t)f2b(f.y) << 16);
    o.y = (uint32_t)f2b(f.z) | ((uint32_t)f2b(f.w) << 16);
    ((uint2*)Xb)[i] = o;
    return;
  }
  bid -= 4096;
  const float* src; uint16_t* dst; int K, N, bx, by;
  if (bid < 2048)       { src = Wq; dst = Wqt; K = 1024; N = 2048; bx = bid & 63; by = bid >> 6; }
  else if (bid < 3072)  { bid -= 2048; src = Wk; dst = Wkt; K = 1024; N = 1024; bx = bid & 31; by = bid >> 5; }
  else if (bid < 4096)  { bid -= 3072; src = Wv; dst = Wvt; K = 1024; N = 1024; bx = bid & 31; by = bid >> 5; }
  else                  { bid -= 4096; src = Wo; dst = Wot; K = 2048; N = 1024; bx = bid & 31; by = bid >> 5; }
  int nb = bx * 32, kb = by * 32;
  int tx = threadIdx.x & 31, ty = threadIdx.x >> 5;
  #pragma unroll
  for (int i = ty; i < 32; i += 8) tt[i][tx] = src[(size_t)(kb + i) * N + nb + tx];
  __syncthreads();
  #pragma unroll
  for (int i = ty; i < 32; i += 8) dst[(size_t)(nb + i) * K + kb + tx] = f2b(tt[tx][i]);
}

// ------------- fused QKV GEMM with norm/rope epilogue -------------
__global__ __launch_bounds__(256) void gemm_qkv(const uint16_t* __restrict__ A,
                                                const uint16_t* __restrict__ Bt,
                                                uint16_t* __restrict__ Qb,
                                                uint16_t* __restrict__ Kb,
                                                uint16_t* __restrict__ Vtb,
                                                const float* __restrict__ qw,
                                                const float* __restrict__ kw,
                                                const float* __restrict__ cosr,
                                                const float* __restrict__ sinr) {
  __shared__ uint16_t Sh[128 * 128];
  uint16_t* Al = Sh;
  uint16_t* Bl = Sh + 128 * 64;
  int tid = threadIdx.x;
  int lane = tid & 63, lr = lane & 15, g = lane >> 4;
  int w = tid >> 6, wm = w >> 1, wn = w & 1;
  int wbase = w * 64;
  int m0 = blockIdx.y * 128, n0 = blockIdx.x * 128;
  f32x4 acc[4][4] = {};
  for (int k0 = 0; k0 < 1024; k0 += 64) {
    __syncthreads();
    #pragma unroll
    for (int p = 0; p < 4; ++p) {
      int c = tid + p * 256;
      int row = c >> 3, cb = c & 7;
      int sc = (cb ^ (row & 7)) * 8;
      gload16(A + (size_t)(m0 + row) * 1024 + k0 + sc, Al + (size_t)(p * 256 + wbase) * 8);
      gload16(Bt + (size_t)(n0 + row) * 1024 + k0 + sc, Bl + (size_t)(p * 256 + wbase) * 8);
    }
    __syncthreads();
    #pragma unroll
    for (int ks = 0; ks < 2; ++ks) {
      bf16x8 af[4], bfr[4];
      #pragma unroll
      for (int mi = 0; mi < 4; ++mi) {
        int row = wm * 64 + mi * 16 + lr;
        af[mi] = *(bf16x8*)((char*)Al + row * 128 + ((ks * 64 + g * 16) ^ ((row & 7) << 4)));
      }
      #pragma unroll
      for (int ni = 0; ni < 4; ++ni) {
        int row = wn * 64 + ni * 16 + lr;
        bfr[ni] = *(bf16x8*)((char*)Bl + row * 128 + ((ks * 64 + g * 16) ^ ((row & 7) << 4)));
      }
      __builtin_amdgcn_s_setprio(1);
      #pragma unroll
      for (int mi = 0; mi < 4; ++mi)
        #pragma unroll
        for (int ni = 0; ni < 4; ++ni)
          acc[mi][ni] = __builtin_amdgcn_mfma_f32_16x16x32_bf16(af[mi], bfr[ni], acc[mi][ni], 0, 0, 0);
      __builtin_amdgcn_s_setprio(0);
    }
  }
  __syncthreads();
  uint16_t* L = Sh;
  #pragma unroll
  for (int mi = 0; mi < 4; ++mi)
    #pragma unroll
    for (int ni = 0; ni < 4; ++ni)
      #pragma unroll
      for (int e = 0; e < 4; ++e) {
        int row = wm * 64 + mi * 16 + 4 * g + e;
        int col = wn * 64 + ni * 16 + lr;
        L[row * 128 + ((((col >> 3) ^ (row & 7)) << 3) | (col & 7))] = f2b(acc[mi][ni][e]);
      }
  __syncthreads();
  int hsel = n0 >> 7;
  if (hsel < 24) {
    int row = tid >> 1, half = tid & 1;
    int gr = m0 + row, bb = gr >> 11, s = gr & 2047;
    int d0 = half * 32;
    float x[64];
    #pragma unroll
    for (int c8 = 0; c8 < 8; ++c8) {
      int jj = (c8 & 3) * 8 + d0 + (c8 >> 2) * 64;
      union { bf16x8 v; uint16_t u[8]; } tmp;
      tmp.v = *(bf16x8*)(L + row * 128 + (((jj >> 3) ^ (row & 7)) << 3));
      #pragma unroll
      for (int k = 0; k < 8; ++k) x[c8 * 8 + k] = b2f(tmp.u[k]);
    }
    float ss = 0.f;
    #pragma unroll
    for (int k = 0; k < 64; ++k) ss += x[k] * x[k];
    ss += __shfl_xor(ss, 1, 64);
    float rn = rsqrtf(ss * (1.0f / 128.0f) + EPS_);
    const float* wv = (hsel < 16) ? qw : kw;
    float scq = (hsel < 16) ? SCALE_ : 1.0f;
    rn *= scq;
    uint16_t* outp = (hsel < 16)
      ? Qb + (((size_t)(bb * 16 + hsel)) * 2048 + s) * 128
      : Kb + (((size_t)(bb * 8 + (hsel - 16))) * 2048 + s) * 128;
    const float* cR = cosr + s * 128;
    const float* sR = sinr + s * 128;
    #pragma unroll
    for (int c = 0; c < 4; ++c) {
      int dlo = d0 + c * 8;
      uint16_t olo[8], ohi[8];
      #pragma unroll
      for (int k = 0; k < 8; ++k) {
        int d = dlo + k;
        float x1 = x[c * 8 + k] * rn * wv[d];
        float x2 = x[32 + c * 8 + k] * rn * wv[d + 64];
        olo[k] = f2b(x1 * cR[d] - x2 * sR[d]);
        ohi[k] = f2b(x2 * cR[d + 64] + x1 * sR[d + 64]);
      }
      *(uint4*)(outp + dlo) = *(uint4*)olo;
      *(uint4*)(outp + 64 + dlo) = *(uint4*)ohi;
    }
  } else {
    int kvh = hsel - 24;
    int d0 = tid >> 1, sh = tid & 1;
    int bb = m0 >> 11, sg0 = (m0 & 2047) + sh * 64;
    union { uint16_t u[64]; uint4 q[8]; } vv;
    #pragma unroll
    for (int sl = 0; sl < 64; ++sl) {
      int srow = sh * 64 + sl;
      vv.u[sl] = L[srow * 128 + ((((d0 >> 3) ^ (srow & 7)) << 3) | (d0 & 7))];
    }
    uint16_t* vt = Vtb + (((size_t)(bb * 8 + kvh)) * 128 + d0) * 2048 + sg0;
    #pragma unroll
    for (int c = 0; c < 8; ++c) *(uint4*)(vt + c * 8) = vv.q[c];
  }
}

// ------------- Vt[bkv][d][s] -> packed Vp[bkv][kb64][dt*4+j][lane][8] -------------
__global__ __launch_bounds__(256) void vrepack(const uint16_t* __restrict__ Vt,
                                               uint16_t* __restrict__ Vp) {
  int bkv = blockIdx.y, p = blockIdx.x;
  const uint16_t* src = Vt + (size_t)bkv * KVSTRIDE_;
  uint16_t* dst = Vp + (size_t)bkv * KVSTRIDE_;
  #pragma unroll
  for (int i = 0; i < 16; ++i) {
    int idx = i * 256 + threadIdx.x;
    int d = idx >> 5, sc = p * 32 + (idx & 31);
    int s8 = sc * 8;
    uint4 v = *(const uint4*)(src + (size_t)d * 2048 + s8);
    int kb64 = s8 >> 6, j = (s8 >> 4) & 3, hh = (s8 >> 3) & 1;
    int dt = d >> 5, qlv = d & 31;
    ((uint4*)dst)[(kb64 * 16 + dt * 4 + j) * 64 + hh * 32 + qlv] = v;
  }
}

// ------------- GEMM BM=128, BN=64 (f32 out) for the O-projection -------------
__global__ __launch_bounds__(256) void gemm_o(const uint16_t* __restrict__ A,
                                              const uint16_t* __restrict__ Bt,
                                              float* __restrict__ Cout,
                                              int M, int N, int K) {
  __shared__ uint16_t Al[128 * 64];
  __shared__ uint16_t Bl[64 * 64];
  int tid = threadIdx.x;
  int lane = tid & 63, lr = lane & 15, g = lane >> 4;
  int w = tid >> 6, wm = w >> 1, wn = w & 1;
  int wbase = w * 64;
  int m0 = blockIdx.y * 128, n0 = blockIdx.x * 64;
  f32x4 acc[4][2] = {};
  for (int k0 = 0; k0 < K; k0 += 64) {
    __syncthreads();
    #pragma unroll
    for (int p = 0; p < 4; ++p) {
      int c = tid + p * 256;
      int row = c >> 3, cb = c & 7;
      int sc = (cb ^ (row & 7)) * 8;
      gload16(A + (size_t)(m0 + row) * K + k0 + sc, Al + (size_t)(p * 256 + wbase) * 8);
    }
    #pragma unroll
    for (int p = 0; p < 2; ++p) {
      int c = tid + p * 256;
      int row = c >> 3, cb = c & 7;
      int sc = (cb ^ (row & 7)) * 8;
      gload16(Bt + (size_t)(n0 + row) * K + k0 + sc, Bl + (size_t)(p * 256 + wbase) * 8);
    }
    __syncthreads();
    #pragma unroll
    for (int ks = 0; ks < 2; ++ks) {
      bf16x8 af[4], bfr[2];
      #pragma unroll
      for (int mi = 0; mi < 4; ++mi) {
        int row = wm * 64 + mi * 16 + lr;
        af[mi] = *(bf16x8*)((char*)Al + row * 128 + ((ks * 64 + g * 16) ^ ((row & 7) << 4)));
      }
      #pragma unroll
      for (int ni = 0; ni < 2; ++ni) {
        int row = wn * 32 + ni * 16 + lr;
        bfr[ni] = *(bf16x8*)((char*)Bl + row * 128 + ((ks * 64 + g * 16) ^ ((row & 7) << 4)));
      }
      __builtin_amdgcn_s_setprio(1);
      #pragma unroll
      for (int mi = 0; mi < 4; ++mi)
        #pragma unroll
        for (int ni = 0; ni < 2; ++ni)
          acc[mi][ni] = __builtin_amdgcn_mfma_f32_16x16x32_bf16(af[mi], bfr[ni], acc[mi][ni], 0, 0, 0);
      __builtin_amdgcn_s_setprio(0);
    }
  }
  #pragma unroll
  for (int mi = 0; mi < 4; ++mi)
    #pragma unroll
    for (int ni = 0; ni < 2; ++ni)
      #pragma unroll
      for (int e = 0; e < 4; ++e) {
        int row = m0 + wm * 64 + mi * 16 + 4 * g + e;
        int col = n0 + wn * 32 + ni * 16 + lr;
        Cout[(size_t)row * N + col] = acc[mi][ni][e];
      }
}

// ------------- causal GQA flash attention: K via shared LDS, V via packed global ---
#define STAGE(BUF, KB) {                                                       \
  int kb64 = (KB) * 64;                                                        \
  _Pragma("unroll") for (int p2 = 0; p2 < 4; ++p2) {                           \
    int ck = p2 * 4 + w;                                                       \
    int krow = ck * 4 + (lane >> 4);                                           \
    int kg = (lane & 15) ^ (krow & 7);                                         \
    gload16(Kg + (size_t)(kb64 + krow) * D_ + kg * 8, Kl[BUF] + ck * 512);     \
  } }

__global__ __launch_bounds__(256, 2) void attn_kernel(const uint16_t* __restrict__ Qb,
                                                      const uint16_t* __restrict__ Kb,
                                                      const uint16_t* __restrict__ Vp,
                                                      uint16_t* __restrict__ out) {
  __shared__ uint16_t Kl[2][64 * 128];
  int tid = threadIdx.x, lane = tid & 63, w = tid >> 6;
  int ql = lane & 31, hi = lane >> 5;
  int bi = blockIdx.x;
  int biH = bi >> 8;
  int j2 = bi & 255;
  int qgl = j2 >> 5;
  int qg = biH ? qgl : 15 - qgl;
  int rem = j2 & 31;
  int bkv = rem >> 1, hsel = rem & 1;
  int b = bkv >> 3, kv = bkv & 7, h = kv * 2 + hsel;
  int qt = qg * 4 + w;
  int q0 = qt * 32;
  int mykb = qt >> 1;
  int kbmax = 2 * qg + 1;
  const uint16_t* Qg = Qb + ((size_t)(b * H_ + h)) * S_ * D_;
  const uint16_t* Kg = Kb + ((size_t)(b * HKV_ + kv)) * S_ * D_;
  const uint16_t* Vpg = Vp + (size_t)(b * HKV_ + kv) * KVSTRIDE_;
  bf16x8 qf[8];
  #pragma unroll
  for (int t = 0; t < 8; ++t)
    qf[t] = *(const bf16x8*)(Qg + (size_t)(q0 + ql) * D_ + t * 16 + 8 * hi);
  f32x16 O[4] = {};
  float mrun = -__builtin_inff();
  float lrun = 0.f;
  STAGE(0, 0)
  for (int kb = 0; kb <= kbmax; ++kb) {
    int cur = kb & 1;
    __syncthreads();
    if (kb < kbmax) STAGE(cur ^ 1, kb + 1)
    if (kb <= mykb) {
      const uint16_t* KlC = Kl[cur];
      const uint16_t* Vb64 = Vpg + (size_t)kb * 8192;
      bool diag = (kb == mykb);
      bool skip2 = diag && ((qt & 1) == 0);
      float p0[16], p1[16];
      {
        bf16x8 kf[8];
        #pragma unroll
        for (int t = 0; t < 8; ++t)
          kf[t] = *(const bf16x8*)(KlC + ql * 128 + (((2 * t + hi) ^ (ql & 7)) * 8));
        f32x16 acc = {};
        __builtin_amdgcn_s_setprio(1);
        #pragma unroll
        for (int t = 0; t < 8; ++t)
          acc = __builtin_amdgcn_mfma_f32_32x32x16_bf16(kf[t], qf[t], acc, 0, 0, 0);
        __builtin_amdgcn_s_setprio(0);
        #pragma unroll
        for (int r = 0; r < 16; ++r) p0[r] = acc[r];
      }
      if (!skip2) {
        bf16x8 kf[8];
        #pragma unroll
        for (int t = 0; t < 8; ++t)
          kf[t] = *(const bf16x8*)(KlC + (32 + ql) * 128 + (((2 * t + hi) ^ (ql & 7)) * 8));
        f32x16 acc = {};
        __builtin_amdgcn_s_setprio(1);
        #pragma unroll
        for (int t = 0; t < 8; ++t)
          acc = __builtin_amdgcn_mfma_f32_32x32x16_bf16(kf[t], qf[t], acc, 0, 0, 0);
        __builtin_amdgcn_s_setprio(0);
        #pragma unroll
        for (int r = 0; r < 16; ++r) p1[r] = acc[r];
      }
      bf16x8 vf[16];
      #pragma unroll
      for (int dt = 0; dt < 4; ++dt) {
        vf[dt * 4 + 0] = *(const bf16x8*)(Vb64 + ((dt * 4 + 0) * 64 + lane) * 8);
        vf[dt * 4 + 1] = *(const bf16x8*)(Vb64 + ((dt * 4 + 1) * 64 + lane) * 8);
      }
      if (!skip2) {
        #pragma unroll
        for (int dt = 0; dt < 4; ++dt) {
          vf[dt * 4 + 2] = *(const bf16x8*)(Vb64 + ((dt * 4 + 2) * 64 + lane) * 8);
          vf[dt * 4 + 3] = *(const bf16x8*)(Vb64 + ((dt * 4 + 3) * 64 + lane) * 8);
        }
      }
      if (diag && !(qt & 1)) {
        #pragma unroll
        for (int r = 0; r < 16; ++r) {
          int kk = kb * 64 + 8 * (r >> 2) + 4 * hi + (r & 3);
          if (kk > q0 + ql) p0[r] = -__builtin_inff();
        }
      }
      if (diag && (qt & 1)) {
        #pragma unroll
        for (int r = 0; r < 16; ++r) {
          int kk = kb * 64 + 32 + 8 * (r >> 2) + 4 * hi + (r & 3);
          if (kk > q0 + ql) p1[r] = -__builtin_inff();
        }
      }
      float m8[8];
      #pragma unroll
      for (int i = 0; i < 8; ++i) m8[i] = fmaxf(p0[i], p0[i + 8]);
      if (!skip2) {
        #pragma unroll
        for (int i = 0; i < 8; ++i) m8[i] = fmaxf(m8[i], fmaxf(p1[i], p1[i + 8]));
      }
      float m4a = fmaxf(m8[0], m8[4]), m4b = fmaxf(m8[1], m8[5]);
      float m4c = fmaxf(m8[2], m8[6]), m4d = fmaxf(m8[3], m8[7]);
      float pmax = fmaxf(fmaxf(m4a, m4b), fmaxf(m4c, m4d));
      pmax = fmaxf(pmax, __shfl_xor(pmax, 32, 64));
      if (__any(pmax > mrun + 8.f)) {
        float mnew = fmaxf(mrun, pmax);
        float rs = __expf(mrun - mnew);
        lrun *= rs;
        #pragma unroll
        for (int r = 0; r < 16; ++r) {
          float rr = __shfl(rs, (r & 3) + 8 * (r >> 2) + 4 * hi, 64);
          #pragma unroll
          for (int dt = 0; dt < 4; ++dt) O[dt][r] *= rr;
        }
        mrun = mnew;
      }
      float ls = 0.f;
      union PW { uint32_t w[4]; bf16x8 v; } pa0, pa1;
      #pragma unroll
      for (int r = 0; r < 16; ++r) { p0[r] = __expf(p0[r] - mrun); ls += p0[r]; }
      {
        uint32_t uu[4][2];
        #pragma unroll
        for (int T = 0; T < 4; ++T) {
          asm("v_cvt_pk_bf16_f32 %0, %1, %2" : "=v"(uu[T][0]) : "v"(p0[4 * T]), "v"(p0[4 * T + 1]));
          asm("v_cvt_pk_bf16_f32 %0, %1, %2" : "=v"(uu[T][1]) : "v"(p0[4 * T + 2]), "v"(p0[4 * T + 3]));
        }
        uint32_t a = uu[0][0], bb2 = uu[1][0];
        asm("v_permlane32_swap_b32 %0, %1" : "+v"(a), "+v"(bb2));
        uint32_t c = uu[0][1], d = uu[1][1];
        asm("v_permlane32_swap_b32 %0, %1" : "+v"(c), "+v"(d));
        pa0.w[0] = a; pa0.w[1] = c; pa0.w[2] = bb2; pa0.w[3] = d;
        uint32_t a2 = uu[2][0], b2 = uu[3][0];
        asm("v_permlane32_swap_b32 %0, %1" : "+v"(a2), "+v"(b2));
        uint32_t c2 = uu[2][1], d2 = uu[3][1];
        asm("v_permlane32_swap_b32 %0, %1" : "+v"(c2), "+v"(d2));
        pa1.w[0] = a2; pa1.w[1] = c2; pa1.w[2] = b2; pa1.w[3] = d2;
      }
      __builtin_amdgcn_s_setprio(1);
      #pragma unroll
      for (int dt = 0; dt < 4; ++dt) {
        O[dt] = __builtin_amdgcn_mfma_f32_32x32x16_bf16(pa0.v, vf[dt * 4 + 0], O[dt], 0, 0, 0);
        O[dt] = __builtin_amdgcn_mfma_f32_32x32x16_bf16(pa1.v, vf[dt * 4 + 1], O[dt], 0, 0, 0);
      }
      __builtin_amdgcn_s_setprio(0);
      if (!skip2) {
        union PW pa2, pa3;
        #pragma unroll
        for (int r = 0; r < 16; ++r) { p1[r] = __expf(p1[r] - mrun); ls += p1[r]; }
        {
          uint32_t uu[4][2];
          #pragma unroll
          for (int T = 0; T < 4; ++T) {
            asm("v_cvt_pk_bf16_f32 %0, %1, %2" : "=v"(uu[T][0]) : "v"(p1[4 * T]), "v"(p1[4 * T + 1]));
            asm("v_cvt_pk_bf16_f32 %0, %1, %2" : "=v"(uu[T][1]) : "v"(p1[4 * T + 2]), "v"(p1[4 * T + 3]));
          }
          uint32_t a = uu[0][0], bb2 = uu[1][0];
          asm("v_permlane32_swap_b32 %0, %1" : "+v"(a), "+v"(bb2));
          uint32_t c = uu[0][1], d = uu[1][1];
          asm("v_permlane32_swap_b32 %0, %1" : "+v"(c), "+v"(d));
          pa2.w[0] = a; pa2.w[1] = c; pa2.w[2] = bb2; pa2.w[3] = d;
          uint32_t a2 = uu[2][0], b2 = uu[3][0];
          asm("v_permlane32_swap_b32 %0, %1" : "+v"(a2), "+v"(b2));
          uint32_t c2 = uu[2][1], d2 = uu[3][1];
          asm("v_permlane32_swap_b32 %0, %1" : "+v"(c2), "+v"(d2));
          pa3.w[0] = a2; pa3.w[1] = c2; pa3.w[2] = b2; pa3.w[3] = d2;
        }
        __builtin_amdgcn_s_setprio(1);
        #pragma unroll
        for (int dt = 0; dt < 4; ++dt) {
          O[dt] = __builtin_amdgcn_mfma_f32_32x32x16_bf16(pa2.v, vf[dt * 4 + 2], O[dt], 0, 0, 0);
          O[dt] = __builtin_amdgcn_mfma_f32_32x32x16_bf16(pa3.v, vf[dt * 4 + 3], O[dt], 0, 0, 0);
        }
        __builtin_amdgcn_s_setprio(0);
      }
      ls += __shfl_xor(ls, 32, 64);
      lrun += ls;
    }
  }
  float linv = 1.0f / lrun;
  #pragma unroll
  for (int r = 0; r < 16; ++r) {
    int qrl = (r & 3) + 8 * (r >> 2) + 4 * hi;
    float lr_ = __shfl(linv, qrl, 64);
    #pragma unroll
    for (int dt = 0; dt < 4; ++dt) {
      size_t o = ((size_t)(b * S_ + q0 + qrl)) * 2048 + h * 128 + dt * 32 + ql;
      out[o] = f2b(O[dt][r] * lr_);
    }
  }
}

extern "C" void kernel_launch(void* const* d_in, const int* in_sizes, int n_in,
                              void* d_out, int out_size, void* d_ws, size_t ws_size,
                              hipStream_t stream) {
  const float* hidden = (const float*)d_in[0];
  const float* cosr = (const float*)d_in[2];
  const float* sinr = (const float*)d_in[3];
  const float* Wq = (const float*)d_in[4];
  const float* Wk = (const float*)d_in[5];
  const float* Wv = (const float*)d_in[6];
  const float* Wo = (const float*)d_in[7];
  const float* qw = (const float*)d_in[8];
  const float* kw = (const float*)d_in[9];

  uint16_t* p = (uint16_t*)d_ws;
  uint16_t* Xb   = p; p += (size_t)4096 * 1024;
  uint16_t* Wqt  = p; p += (size_t)2048 * 1024;   // Wqt|Wkt|Wvt contiguous fused B^T
  uint16_t* Wkt  = p; p += (size_t)1024 * 1024;
  uint16_t* Wvt  = p; p += (size_t)1024 * 1024;
  uint16_t* Wot  = p; p += (size_t)1024 * 2048;
  uint16_t* Qbuf = p; p += (size_t)B_ * H_ * S_ * D_;
  uint16_t* Kbuf = p; p += (size_t)B_ * HKV_ * S_ * D_;
  uint16_t* Vtb  = p; p += (size_t)B_ * HKV_ * S_ * D_;   // V^T [bkv][128][2048]
  uint16_t* attn = p; p += (size_t)4096 * 2048;
  uint16_t* Vpb  = Xb;  // packed V fragments; aliases Xb (dead after gemm_qkv)

  prep<<<10240, 256, 0, stream>>>(hidden, Xb, Wq, Wk, Wv, Wo, Wqt, Wkt, Wvt, Wot);
  gemm_qkv<<<dim3(32, 32), 256, 0, stream>>>(Xb, Wqt, Qbuf, Kbuf, Vtb, qw, kw, cosr, sinr);
  vrepack<<<dim3(8, 16), 256, 0, stream>>>(Vtb, Vpb);
  attn_kernel<<<512, 256, 0, stream>>>(Qbuf, Kbuf, Vpb, attn);
  gemm_o<<<dim3(16, 32), 256, 0, stream>>>(attn, Wot, (float*)d_out, 4096, 1024, 2048);
}

// Round 17
// 171.833 us; speedup vs baseline: 2.2355x; 1.0208x over previous
//
#include <hip/hip_runtime.h>
#include <stdint.h>

#define B_ 2
#define S_ 2048
#define H_ 16
#define HKV_ 8
#define D_ 128
#define EPS_ 1e-6f
#define SCALE_ 0.08838834764831845f
#define KVSTRIDE_ 262144   // per (b,kv): 2048*128 elems

typedef __attribute__((ext_vector_type(8))) __bf16 bf16x8;
typedef __attribute__((ext_vector_type(4))) float f32x4;
typedef __attribute__((ext_vector_type(16))) float f32x16;

static __device__ __forceinline__ uint16_t f2b(float f) {
  uint32_t u = __builtin_bit_cast(uint32_t, f);
  u += 0x7fffu + ((u >> 16) & 1u);
  return (uint16_t)(u >> 16);
}
static __device__ __forceinline__ float b2f(uint16_t b) {
  uint32_t u = ((uint32_t)b) << 16;
  return __builtin_bit_cast(float, u);
}

typedef const __attribute__((address_space(1))) uint32_t* gas_p;
typedef __attribute__((address_space(3))) uint32_t* las_p;
static __device__ __forceinline__ void gload16(const void* g, void* l) {
  __builtin_amdgcn_global_load_lds((gas_p)g, (las_p)l, 16, 0, 0);
}

// ------------- prep: castk (blocks 0..4095) + 4 weight transposes -------------
__global__ __launch_bounds__(256) void prep(const float* __restrict__ hidden,
                                            uint16_t* __restrict__ Xb,
                                            const float* __restrict__ Wq,
                                            const float* __restrict__ Wk,
                                            const float* __restrict__ Wv,
                                            const float* __restrict__ Wo,
                                            uint16_t* __restrict__ Wqt,
                                            uint16_t* __restrict__ Wkt,
                                            uint16_t* __restrict__ Wvt,
                                            uint16_t* __restrict__ Wot) {
  __shared__ float tt[32][33];
  int bid = blockIdx.x;
  if (bid < 4096) {
    int i = bid * 256 + threadIdx.x;
    float4 f = ((const float4*)hidden)[i];
    uint2 o;
    o.x = (uint32_t)f2b(f.x) | ((uint32_t)f2b(f.y) << 16);
    o.y = (uint32_t)f2b(f.z) | ((uint32_t)f2b(f.w) << 16);
    ((uint2*)Xb)[i] = o;
    return;
  }
  bid -= 4096;
  const float* src; uint16_t* dst; int K, N, bx, by;
  if (bid < 2048)       { src = Wq; dst = Wqt; K = 1024; N = 2048; bx = bid & 63; by = bid >> 6; }
  else if (bid < 3072)  { bid -= 2048; src = Wk; dst = Wkt; K = 1024; N = 1024; bx = bid & 31; by = bid >> 5; }
  else if (bid < 4096)  { bid -= 3072; src = Wv; dst = Wvt; K = 1024; N = 1024; bx = bid & 31; by = bid >> 5; }
  else                  { bid -= 4096; src = Wo; dst = Wot; K = 2048; N = 1024; bx = bid & 31; by = bid >> 5; }
  int nb = bx * 32, kb = by * 32;
  int tx = threadIdx.x & 31, ty = threadIdx.x >> 5;
  #pragma unroll
  for (int i = ty; i < 32; i += 8) tt[i][tx] = src[(size_t)(kb + i) * N + nb + tx];
  __syncthreads();
  #pragma unroll
  for (int i = ty; i < 32; i += 8) dst[(size_t)(nb + i) * K + kb + tx] = f2b(tt[tx][i]);
}

// ------------- fused QKV GEMM with norm/rope epilogue -------------
// Q/K -> RMSNorm+RoPE(+SCALE for Q), row-major (b,head,s,d); V -> packed
// fragments Vp[bkv][kb64][dt*4+j][lane][8] directly (replaces Vt + vrepack).
__global__ __launch_bounds__(256) void gemm_qkv(const uint16_t* __restrict__ A,
                                                const uint16_t* __restrict__ Bt,
                                                uint16_t* __restrict__ Qb,
                                                uint16_t* __restrict__ Kb,
                                                uint16_t* __restrict__ Vp,
                                                const float* __restrict__ qw,
                                                const float* __restrict__ kw,
                                                const float* __restrict__ cosr,
                                                const float* __restrict__ sinr) {
  __shared__ uint16_t Sh[128 * 128];
  uint16_t* Al = Sh;
  uint16_t* Bl = Sh + 128 * 64;
  int tid = threadIdx.x;
  int lane = tid & 63, lr = lane & 15, g = lane >> 4;
  int w = tid >> 6, wm = w >> 1, wn = w & 1;
  int wbase = w * 64;
  int m0 = blockIdx.y * 128, n0 = blockIdx.x * 128;
  f32x4 acc[4][4] = {};
  for (int k0 = 0; k0 < 1024; k0 += 64) {
    __syncthreads();
    #pragma unroll
    for (int p = 0; p < 4; ++p) {
      int c = tid + p * 256;
      int row = c >> 3, cb = c & 7;
      int sc = (cb ^ (row & 7)) * 8;
      gload16(A + (size_t)(m0 + row) * 1024 + k0 + sc, Al + (size_t)(p * 256 + wbase) * 8);
      gload16(Bt + (size_t)(n0 + row) * 1024 + k0 + sc, Bl + (size_t)(p * 256 + wbase) * 8);
    }
    __syncthreads();
    #pragma unroll
    for (int ks = 0; ks < 2; ++ks) {
      bf16x8 af[4], bfr[4];
      #pragma unroll
      for (int mi = 0; mi < 4; ++mi) {
        int row = wm * 64 + mi * 16 + lr;
        af[mi] = *(bf16x8*)((char*)Al + row * 128 + ((ks * 64 + g * 16) ^ ((row & 7) << 4)));
      }
      #pragma unroll
      for (int ni = 0; ni < 4; ++ni) {
        int row = wn * 64 + ni * 16 + lr;
        bfr[ni] = *(bf16x8*)((char*)Bl + row * 128 + ((ks * 64 + g * 16) ^ ((row & 7) << 4)));
      }
      __builtin_amdgcn_s_setprio(1);
      #pragma unroll
      for (int mi = 0; mi < 4; ++mi)
        #pragma unroll
        for (int ni = 0; ni < 4; ++ni)
          acc[mi][ni] = __builtin_amdgcn_mfma_f32_16x16x32_bf16(af[mi], bfr[ni], acc[mi][ni], 0, 0, 0);
      __builtin_amdgcn_s_setprio(0);
    }
  }
  __syncthreads();
  uint16_t* L = Sh;
  #pragma unroll
  for (int mi = 0; mi < 4; ++mi)
    #pragma unroll
    for (int ni = 0; ni < 4; ++ni)
      #pragma unroll
      for (int e = 0; e < 4; ++e) {
        int row = wm * 64 + mi * 16 + 4 * g + e;
        int col = wn * 64 + ni * 16 + lr;
        L[row * 128 + ((((col >> 3) ^ (row & 7)) << 3) | (col & 7))] = f2b(acc[mi][ni][e]);
      }
  __syncthreads();
  int hsel = n0 >> 7;   // 0..15 Q-head, 16..23 K-head, 24..31 V-head
  if (hsel < 24) {
    int row = tid >> 1, half = tid & 1;
    int gr = m0 + row, bb = gr >> 11, s = gr & 2047;
    int d0 = half * 32;
    float x[64];
    #pragma unroll
    for (int c8 = 0; c8 < 8; ++c8) {
      int jj = (c8 & 3) * 8 + d0 + (c8 >> 2) * 64;
      union { bf16x8 v; uint16_t u[8]; } tmp;
      tmp.v = *(bf16x8*)(L + row * 128 + (((jj >> 3) ^ (row & 7)) << 3));
      #pragma unroll
      for (int k = 0; k < 8; ++k) x[c8 * 8 + k] = b2f(tmp.u[k]);
    }
    float ss = 0.f;
    #pragma unroll
    for (int k = 0; k < 64; ++k) ss += x[k] * x[k];
    ss += __shfl_xor(ss, 1, 64);
    float rn = rsqrtf(ss * (1.0f / 128.0f) + EPS_);
    const float* wv = (hsel < 16) ? qw : kw;
    float scq = (hsel < 16) ? SCALE_ : 1.0f;
    rn *= scq;
    uint16_t* outp = (hsel < 16)
      ? Qb + (((size_t)(bb * 16 + hsel)) * 2048 + s) * 128
      : Kb + (((size_t)(bb * 8 + (hsel - 16))) * 2048 + s) * 128;
    const float* cR = cosr + s * 128;
    const float* sR = sinr + s * 128;
    #pragma unroll
    for (int c = 0; c < 4; ++c) {
      int dlo = d0 + c * 8;
      uint16_t olo[8], ohi[8];
      #pragma unroll
      for (int k = 0; k < 8; ++k) {
        int d = dlo + k;
        float x1 = x[c * 8 + k] * rn * wv[d];
        float x2 = x[32 + c * 8 + k] * rn * wv[d + 64];
        olo[k] = f2b(x1 * cR[d] - x2 * sR[d]);
        ohi[k] = f2b(x2 * cR[d + 64] + x1 * sR[d + 64]);
      }
      *(uint4*)(outp + dlo) = *(uint4*)olo;
      *(uint4*)(outp + 64 + dlo) = *(uint4*)ohi;
    }
  } else {
    // V: packed-fragment store (verified R10; byte-identical to vrepack output)
    int kvh = hsel - 24;
    int d0 = tid >> 1, sh = tid & 1;
    int bb = m0 >> 11, sg0 = (m0 & 2047) + sh * 64;
    union { uint16_t u[64]; uint4 q[8]; } vv;
    #pragma unroll
    for (int sl = 0; sl < 64; ++sl) {
      int srow = sh * 64 + sl;
      vv.u[sl] = L[srow * 128 + ((((d0 >> 3) ^ (srow & 7)) << 3) | (d0 & 7))];
    }
    uint16_t* vp = Vp + (size_t)(bb * 8 + kvh) * KVSTRIDE_;
    int dt = d0 >> 5, qlv = d0 & 31;
    #pragma unroll
    for (int c = 0; c < 8; ++c) {
      int s8 = sg0 + c * 8;
      int kb64 = s8 >> 6, j = (s8 & 63) >> 4, hh = (s8 >> 3) & 1;
      *(uint4*)(vp + ((((size_t)kb64 * 16) + dt * 4 + j) * 64 + hh * 32 + qlv) * 8) = vv.q[c];
    }
  }
}

// ------------- GEMM BM=128, BN=64 (f32 out) for the O-projection -------------
__global__ __launch_bounds__(256) void gemm_o(const uint16_t* __restrict__ A,
                                              const uint16_t* __restrict__ Bt,
                                              float* __restrict__ Cout,
                                              int M, int N, int K) {
  __shared__ uint16_t Al[128 * 64];
  __shared__ uint16_t Bl[64 * 64];
  int tid = threadIdx.x;
  int lane = tid & 63, lr = lane & 15, g = lane >> 4;
  int w = tid >> 6, wm = w >> 1, wn = w & 1;
  int wbase = w * 64;
  int m0 = blockIdx.y * 128, n0 = blockIdx.x * 64;
  f32x4 acc[4][2] = {};
  for (int k0 = 0; k0 < K; k0 += 64) {
    __syncthreads();
    #pragma unroll
    for (int p = 0; p < 4; ++p) {
      int c = tid + p * 256;
      int row = c >> 3, cb = c & 7;
      int sc = (cb ^ (row & 7)) * 8;
      gload16(A + (size_t)(m0 + row) * K + k0 + sc, Al + (size_t)(p * 256 + wbase) * 8);
    }
    #pragma unroll
    for (int p = 0; p < 2; ++p) {
      int c = tid + p * 256;
      int row = c >> 3, cb = c & 7;
      int sc = (cb ^ (row & 7)) * 8;
      gload16(Bt + (size_t)(n0 + row) * K + k0 + sc, Bl + (size_t)(p * 256 + wbase) * 8);
    }
    __syncthreads();
    #pragma unroll
    for (int ks = 0; ks < 2; ++ks) {
      bf16x8 af[4], bfr[2];
      #pragma unroll
      for (int mi = 0; mi < 4; ++mi) {
        int row = wm * 64 + mi * 16 + lr;
        af[mi] = *(bf16x8*)((char*)Al + row * 128 + ((ks * 64 + g * 16) ^ ((row & 7) << 4)));
      }
      #pragma unroll
      for (int ni = 0; ni < 2; ++ni) {
        int row = wn * 32 + ni * 16 + lr;
        bfr[ni] = *(bf16x8*)((char*)Bl + row * 128 + ((ks * 64 + g * 16) ^ ((row & 7) << 4)));
      }
      __builtin_amdgcn_s_setprio(1);
      #pragma unroll
      for (int mi = 0; mi < 4; ++mi)
        #pragma unroll
        for (int ni = 0; ni < 2; ++ni)
          acc[mi][ni] = __builtin_amdgcn_mfma_f32_16x16x32_bf16(af[mi], bfr[ni], acc[mi][ni], 0, 0, 0);
      __builtin_amdgcn_s_setprio(0);
    }
  }
  #pragma unroll
  for (int mi = 0; mi < 4; ++mi)
    #pragma unroll
    for (int ni = 0; ni < 2; ++ni)
      #pragma unroll
      for (int e = 0; e < 4; ++e) {
        int row = m0 + wm * 64 + mi * 16 + 4 * g + e;
        int col = n0 + wn * 32 + ni * 16 + lr;
        Cout[(size_t)row * N + col] = acc[mi][ni][e];
      }
}

// ------------- causal GQA flash attention: K via shared LDS, V via packed global ---
#define STAGE(BUF, KB) {                                                       \
  int kb64 = (KB) * 64;                                                        \
  _Pragma("unroll") for (int p2 = 0; p2 < 4; ++p2) {                           \
    int ck = p2 * 4 + w;                                                       \
    int krow = ck * 4 + (lane >> 4);                                           \
    int kg = (lane & 15) ^ (krow & 7);                                         \
    gload16(Kg + (size_t)(kb64 + krow) * D_ + kg * 8, Kl[BUF] + ck * 512);     \
  } }

__global__ __launch_bounds__(256, 2) void attn_kernel(const uint16_t* __restrict__ Qb,
                                                      const uint16_t* __restrict__ Kb,
                                                      const uint16_t* __restrict__ Vp,
                                                      uint16_t* __restrict__ out) {
  __shared__ uint16_t Kl[2][64 * 128];
  int tid = threadIdx.x, lane = tid & 63, w = tid >> 6;
  int ql = lane & 31, hi = lane >> 5;
  int bi = blockIdx.x;
  int biH = bi >> 8;
  int j2 = bi & 255;
  int qgl = j2 >> 5;
  int qg = biH ? qgl : 15 - qgl;
  int rem = j2 & 31;
  int bkv = rem >> 1, hsel = rem & 1;
  int b = bkv >> 3, kv = bkv & 7, h = kv * 2 + hsel;
  int qt = qg * 4 + w;
  int q0 = qt * 32;
  int mykb = qt >> 1;
  int kbmax = 2 * qg + 1;
  const uint16_t* Qg = Qb + ((size_t)(b * H_ + h)) * S_ * D_;
  const uint16_t* Kg = Kb + ((size_t)(b * HKV_ + kv)) * S_ * D_;
  const uint16_t* Vpg = Vp + (size_t)(b * HKV_ + kv) * KVSTRIDE_;
  bf16x8 qf[8];
  #pragma unroll
  for (int t = 0; t < 8; ++t)
    qf[t] = *(const bf16x8*)(Qg + (size_t)(q0 + ql) * D_ + t * 16 + 8 * hi);
  f32x16 O[4] = {};
  float mrun = -__builtin_inff();
  float lrun = 0.f;
  STAGE(0, 0)
  for (int kb = 0; kb <= kbmax; ++kb) {
    int cur = kb & 1;
    __syncthreads();
    if (kb < kbmax) STAGE(cur ^ 1, kb + 1)
    if (kb <= mykb) {
      const uint16_t* KlC = Kl[cur];
      const uint16_t* Vb64 = Vpg + (size_t)kb * 8192;
      bool diag = (kb == mykb);
      bool skip2 = diag && ((qt & 1) == 0);
      float p0[16], p1[16];
      {
        bf16x8 kf[8];
        #pragma unroll
        for (int t = 0; t < 8; ++t)
          kf[t] = *(const bf16x8*)(KlC + ql * 128 + (((2 * t + hi) ^ (ql & 7)) * 8));
        f32x16 acc = {};
        __builtin_amdgcn_s_setprio(1);
        #pragma unroll
        for (int t = 0; t < 8; ++t)
          acc = __builtin_amdgcn_mfma_f32_32x32x16_bf16(kf[t], qf[t], acc, 0, 0, 0);
        __builtin_amdgcn_s_setprio(0);
        #pragma unroll
        for (int r = 0; r < 16; ++r) p0[r] = acc[r];
      }
      if (!skip2) {
        bf16x8 kf[8];
        #pragma unroll
        for (int t = 0; t < 8; ++t)
          kf[t] = *(const bf16x8*)(KlC + (32 + ql) * 128 + (((2 * t + hi) ^ (ql & 7)) * 8));
        f32x16 acc = {};
        __builtin_amdgcn_s_setprio(1);
        #pragma unroll
        for (int t = 0; t < 8; ++t)
          acc = __builtin_amdgcn_mfma_f32_32x32x16_bf16(kf[t], qf[t], acc, 0, 0, 0);
        __builtin_amdgcn_s_setprio(0);
        #pragma unroll
        for (int r = 0; r < 16; ++r) p1[r] = acc[r];
      }
      bf16x8 vf[16];
      #pragma unroll
      for (int dt = 0; dt < 4; ++dt) {
        vf[dt * 4 + 0] = *(const bf16x8*)(Vb64 + ((dt * 4 + 0) * 64 + lane) * 8);
        vf[dt * 4 + 1] = *(const bf16x8*)(Vb64 + ((dt * 4 + 1) * 64 + lane) * 8);
      }
      if (!skip2) {
        #pragma unroll
        for (int dt = 0; dt < 4; ++dt) {
          vf[dt * 4 + 2] = *(const bf16x8*)(Vb64 + ((dt * 4 + 2) * 64 + lane) * 8);
          vf[dt * 4 + 3] = *(const bf16x8*)(Vb64 + ((dt * 4 + 3) * 64 + lane) * 8);
        }
      }
      if (diag && !(qt & 1)) {
        #pragma unroll
        for (int r = 0; r < 16; ++r) {
          int kk = kb * 64 + 8 * (r >> 2) + 4 * hi + (r & 3);
          if (kk > q0 + ql) p0[r] = -__builtin_inff();
        }
      }
      if (diag && (qt & 1)) {
        #pragma unroll
        for (int r = 0; r < 16; ++r) {
          int kk = kb * 64 + 32 + 8 * (r >> 2) + 4 * hi + (r & 3);
          if (kk > q0 + ql) p1[r] = -__builtin_inff();
        }
      }
      float m8[8];
      #pragma unroll
      for (int i = 0; i < 8; ++i) m8[i] = fmaxf(p0[i], p0[i + 8]);
      if (!skip2) {
        #pragma unroll
        for (int i = 0; i < 8; ++i) m8[i] = fmaxf(m8[i], fmaxf(p1[i], p1[i + 8]));
      }
      float m4a = fmaxf(m8[0], m8[4]), m4b = fmaxf(m8[1], m8[5]);
      float m4c = fmaxf(m8[2], m8[6]), m4d = fmaxf(m8[3], m8[7]);
      float pmax = fmaxf(fmaxf(m4a, m4b), fmaxf(m4c, m4d));
      pmax = fmaxf(pmax, __shfl_xor(pmax, 32, 64));
      if (__any(pmax > mrun + 8.f)) {
        float mnew = fmaxf(mrun, pmax);
        float rs = __expf(mrun - mnew);
        lrun *= rs;
        #pragma unroll
        for (int r = 0; r < 16; ++r) {
          float rr = __shfl(rs, (r & 3) + 8 * (r >> 2) + 4 * hi, 64);
          #pragma unroll
          for (int dt = 0; dt < 4; ++dt) O[dt][r] *= rr;
        }
        mrun = mnew;
      }
      float ls = 0.f;
      union PW { uint32_t w[4]; bf16x8 v; } pa0, pa1;
      #pragma unroll
      for (int r = 0; r < 16; ++r) { p0[r] = __expf(p0[r] - mrun); ls += p0[r]; }
      {
        uint32_t uu[4][2];
        #pragma unroll
        for (int T = 0; T < 4; ++T) {
          asm("v_cvt_pk_bf16_f32 %0, %1, %2" : "=v"(uu[T][0]) : "v"(p0[4 * T]), "v"(p0[4 * T + 1]));
          asm("v_cvt_pk_bf16_f32 %0, %1, %2" : "=v"(uu[T][1]) : "v"(p0[4 * T + 2]), "v"(p0[4 * T + 3]));
        }
        uint32_t a = uu[0][0], bb2 = uu[1][0];
        asm("v_permlane32_swap_b32 %0, %1" : "+v"(a), "+v"(bb2));
        uint32_t c = uu[0][1], d = uu[1][1];
        asm("v_permlane32_swap_b32 %0, %1" : "+v"(c), "+v"(d));
        pa0.w[0] = a; pa0.w[1] = c; pa0.w[2] = bb2; pa0.w[3] = d;
        uint32_t a2 = uu[2][0], b2 = uu[3][0];
        asm("v_permlane32_swap_b32 %0, %1" : "+v"(a2), "+v"(b2));
        uint32_t c2 = uu[2][1], d2 = uu[3][1];
        asm("v_permlane32_swap_b32 %0, %1" : "+v"(c2), "+v"(d2));
        pa1.w[0] = a2; pa1.w[1] = c2; pa1.w[2] = b2; pa1.w[3] = d2;
      }
      __builtin_amdgcn_s_setprio(1);
      #pragma unroll
      for (int dt = 0; dt < 4; ++dt) {
        O[dt] = __builtin_amdgcn_mfma_f32_32x32x16_bf16(pa0.v, vf[dt * 4 + 0], O[dt], 0, 0, 0);
        O[dt] = __builtin_amdgcn_mfma_f32_32x32x16_bf16(pa1.v, vf[dt * 4 + 1], O[dt], 0, 0, 0);
      }
      __builtin_amdgcn_s_setprio(0);
      if (!skip2) {
        union PW pa2, pa3;
        #pragma unroll
        for (int r = 0; r < 16; ++r) { p1[r] = __expf(p1[r] - mrun); ls += p1[r]; }
        {
          uint32_t uu[4][2];
          #pragma unroll
          for (int T = 0; T < 4; ++T) {
            asm("v_cvt_pk_bf16_f32 %0, %1, %2" : "=v"(uu[T][0]) : "v"(p1[4 * T]), "v"(p1[4 * T + 1]));
            asm("v_cvt_pk_bf16_f32 %0, %1, %2" : "=v"(uu[T][1]) : "v"(p1[4 * T + 2]), "v"(p1[4 * T + 3]));
          }
          uint32_t a = uu[0][0], bb2 = uu[1][0];
          asm("v_permlane32_swap_b32 %0, %1" : "+v"(a), "+v"(bb2));
          uint32_t c = uu[0][1], d = uu[1][1];
          asm("v_permlane32_swap_b32 %0, %1" : "+v"(c), "+v"(d));
          pa2.w[0] = a; pa2.w[1] = c; pa2.w[2] = bb2; pa2.w[3] = d;
          uint32_t a2 = uu[2][0], b2 = uu[3][0];
          asm("v_permlane32_swap_b32 %0, %1" : "+v"(a2), "+v"(b2));
          uint32_t c2 = uu[2][1], d2 = uu[3][1];
          asm("v_permlane32_swap_b32 %0, %1" : "+v"(c2), "+v"(d2));
          pa3.w[0] = a2; pa3.w[1] = c2; pa3.w[2] = b2; pa3.w[3] = d2;
        }
        __builtin_amdgcn_s_setprio(1);
        #pragma unroll
        for (int dt = 0; dt < 4; ++dt) {
          O[dt] = __builtin_amdgcn_mfma_f32_32x32x16_bf16(pa2.v, vf[dt * 4 + 2], O[dt], 0, 0, 0);
          O[dt] = __builtin_amdgcn_mfma_f32_32x32x16_bf16(pa3.v, vf[dt * 4 + 3], O[dt], 0, 0, 0);
        }
        __builtin_amdgcn_s_setprio(0);
      }
      ls += __shfl_xor(ls, 32, 64);
      lrun += ls;
    }
  }
  float linv = 1.0f / lrun;
  #pragma unroll
  for (int r = 0; r < 16; ++r) {
    int qrl = (r & 3) + 8 * (r >> 2) + 4 * hi;
    float lr_ = __shfl(linv, qrl, 64);
    #pragma unroll
    for (int dt = 0; dt < 4; ++dt) {
      size_t o = ((size_t)(b * S_ + q0 + qrl)) * 2048 + h * 128 + dt * 32 + ql;
      out[o] = f2b(O[dt][r] * lr_);
    }
  }
}

extern "C" void kernel_launch(void* const* d_in, const int* in_sizes, int n_in,
                              void* d_out, int out_size, void* d_ws, size_t ws_size,
                              hipStream_t stream) {
  const float* hidden = (const float*)d_in[0];
  const float* cosr = (const float*)d_in[2];
  const float* sinr = (const float*)d_in[3];
  const float* Wq = (const float*)d_in[4];
  const float* Wk = (const float*)d_in[5];
  const float* Wv = (const float*)d_in[6];
  const float* Wo = (const float*)d_in[7];
  const float* qw = (const float*)d_in[8];
  const float* kw = (const float*)d_in[9];

  uint16_t* p = (uint16_t*)d_ws;
  uint16_t* Xb   = p; p += (size_t)4096 * 1024;
  uint16_t* Wqt  = p; p += (size_t)2048 * 1024;   // Wqt|Wkt|Wvt contiguous fused B^T
  uint16_t* Wkt  = p; p += (size_t)1024 * 1024;
  uint16_t* Wvt  = p; p += (size_t)1024 * 1024;
  uint16_t* Wot  = p; p += (size_t)1024 * 2048;
  uint16_t* Qbuf = p; p += (size_t)B_ * H_ * S_ * D_;
  uint16_t* Kbuf = p; p += (size_t)B_ * HKV_ * S_ * D_;
  uint16_t* Vpb  = p; p += (size_t)B_ * HKV_ * S_ * D_;   // packed V fragments
  uint16_t* attn = p; p += (size_t)4096 * 2048;

  prep<<<10240, 256, 0, stream>>>(hidden, Xb, Wq, Wk, Wv, Wo, Wqt, Wkt, Wvt, Wot);
  gemm_qkv<<<dim3(32, 32), 256, 0, stream>>>(Xb, Wqt, Qbuf, Kbuf, Vpb, qw, kw, cosr, sinr);
  attn_kernel<<<512, 256, 0, stream>>>(Qbuf, Kbuf, Vpb, attn);
  gemm_o<<<dim3(16, 32), 256, 0, stream>>>(attn, Wot, (float*)d_out, 4096, 1024, 2048);
}